// Round 8
// baseline (1009.610 us; speedup 1.0000x reference)
//
#include <hip/hip_runtime.h>
#include <hip/hip_bf16.h>

// CrystalHypergraphConv — MI355X implementation.
//
// Decomposition: z[e] = A[idx0[e]] + C[idx1[e]] where
//   A = h @ (lin_w[0:128]+lin_w[256:384]) + lin_b   [N,256]
//   C = connect_feats @ lin_w[128:256]              [NHE,256]
// C stored bf16-packed; lane l owns channels {2l,2l+1,128+2l,129+2l}.
//
// R7 -> R8:
//  * k_aggr was VALU-bound (90%): log2e folded into per-node constants, raw
//    v_exp_f32/v_log_f32 (exp2/log2 builtins), branch-free softplus. ~30% fewer ops.
//  * k_stats: BN1 sums decomposed: Sz = Sdeg*A + Scnt1*C (dense), Sz^2 =
//    Sdeg*A^2 + Scnt1*C^2 (dense) + 2*S_n A.S[n] (edge pass k_cross, node-
//    parallel, branch-free, prefetch). cnt1 histogram fused into k_scatter.
//  * 256-col GEMMs: 2 cols/thread -> each LDS broadcast float4 feeds 8 FMAs.

#define EPS_BN 1e-5f
#define LOG2E 1.4426950408889634f
#define LN2   0.6931471805599453f

__device__ __forceinline__ float fexp2(float x) {
#if __has_builtin(__builtin_amdgcn_exp2f)
    return __builtin_amdgcn_exp2f(x);
#else
    return __expf(x * LN2);
#endif
}
__device__ __forceinline__ float flog2(float x) {
#if __has_builtin(__builtin_amdgcn_logf)
    return __builtin_amdgcn_logf(x);
#else
    return __logf(x) * LOG2E;
#endif
}
// branch-free softplus; safe for |x| < ~80 (data is BN-normalized, |x|<~10)
__device__ __forceinline__ float softplus_fast(float x) {
    return LN2 * flog2(1.f + fexp2(x * LOG2E));
}

__device__ __forceinline__ unsigned short f2bf(float f) {
    unsigned u = __float_as_uint(f);
    unsigned r = (u + 0x7fffu + ((u >> 16) & 1u)) >> 16;   // RNE
    return (unsigned short)r;
}
__device__ __forceinline__ float bflo(unsigned u) { return __uint_as_float(u << 16); }
__device__ __forceinline__ float bfhi(unsigned u) { return __uint_as_float(u & 0xffff0000u); }
__device__ __forceinline__ float bfu16(unsigned short v) { return __uint_as_float(((unsigned)v) << 16); }

// packed channel permutation for NCOL=256
__device__ __forceinline__ int perm256(int j) {
    return (j < 128) ? ((j >> 1) * 4 + (j & 1)) : (((j - 128) >> 1) * 4 + 2 + (j & 1));
}

// ---------------- dense GEMM, NCOL=128 (natural out) ----------------
template<int K, int ROWS>
__global__ __launch_bounds__(128) void gemm_rows(
    const float* __restrict__ in, const float* __restrict__ W,
    const float* __restrict__ bias, float* __restrict__ out, int M)
{
    static_assert(K % 4 == 0, "");
    __shared__ __align__(16) float xs[ROWS * K];
    const int j = threadIdx.x;
    const int r0 = blockIdx.x * ROWS;
    for (int i = j; i < ROWS * K; i += 128) {
        int r = i / K;
        int kk = i - r * K;
        int gi = r0 + r;
        xs[i] = (gi < M) ? in[(size_t)gi * K + kk] : 0.f;
    }
    __syncthreads();
    float b = bias ? bias[j] : 0.f;
    float acc[ROWS];
#pragma unroll
    for (int r = 0; r < ROWS; r++) acc[r] = b;
#pragma unroll 2
    for (int k4 = 0; k4 < K / 4; k4++) {
        const float* Wk = W + (size_t)(4 * k4) * 128 + j;
        float w0 = Wk[0], w1 = Wk[128], w2 = Wk[256], w3 = Wk[384];
#pragma unroll
        for (int r = 0; r < ROWS; r++) {
            float4 xv = *(const float4*)(xs + r * K + 4 * k4);
            acc[r] = fmaf(xv.x, w0, acc[r]);
            acc[r] = fmaf(xv.y, w1, acc[r]);
            acc[r] = fmaf(xv.z, w2, acc[r]);
            acc[r] = fmaf(xv.w, w3, acc[r]);
        }
    }
#pragma unroll
    for (int r = 0; r < ROWS; r++) {
        int gi = r0 + r;
        if (gi < M) out[(size_t)gi * 128 + j] = acc[r];
    }
}

// ---------------- dense GEMM, NCOL=256, 2 cols/thread, packed output ----------------
// OMODE: 1 = packed f32 (A), 2 = packed bf16 (C)
template<int K, int ROWS, int OMODE>
__global__ __launch_bounds__(128) void gemm_rows2(
    const float* __restrict__ in, const float* __restrict__ W,
    const float* __restrict__ bias, void* __restrict__ outv, int M)
{
    static_assert(K % 4 == 0, "");
    __shared__ __align__(16) float xs[ROWS * K];
    const int j = threadIdx.x;            // cols j and j+128
    const int r0 = blockIdx.x * ROWS;
    for (int i = j; i < ROWS * K; i += 128) {
        int r = i / K;
        int kk = i - r * K;
        int gi = r0 + r;
        xs[i] = (gi < M) ? in[(size_t)gi * K + kk] : 0.f;
    }
    __syncthreads();
    float b0 = bias ? bias[j] : 0.f;
    float b1 = bias ? bias[j + 128] : 0.f;
    float acc0[ROWS], acc1[ROWS];
#pragma unroll
    for (int r = 0; r < ROWS; r++) { acc0[r] = b0; acc1[r] = b1; }
#pragma unroll 2
    for (int k4 = 0; k4 < K / 4; k4++) {
        const float* Wk = W + (size_t)(4 * k4) * 256 + j;
        float w00 = Wk[0],   w01 = Wk[128];
        float w10 = Wk[256], w11 = Wk[384];
        float w20 = Wk[512], w21 = Wk[640];
        float w30 = Wk[768], w31 = Wk[896];
#pragma unroll
        for (int r = 0; r < ROWS; r++) {
            float4 xv = *(const float4*)(xs + r * K + 4 * k4);   // wave-broadcast b128
            acc0[r] = fmaf(xv.x, w00, acc0[r]); acc1[r] = fmaf(xv.x, w01, acc1[r]);
            acc0[r] = fmaf(xv.y, w10, acc0[r]); acc1[r] = fmaf(xv.y, w11, acc1[r]);
            acc0[r] = fmaf(xv.z, w20, acc0[r]); acc1[r] = fmaf(xv.z, w21, acc1[r]);
            acc0[r] = fmaf(xv.w, w30, acc0[r]); acc1[r] = fmaf(xv.w, w31, acc1[r]);
        }
    }
    const int pj0 = perm256(j);
    const int pj1 = perm256(j + 128);
#pragma unroll
    for (int r = 0; r < ROWS; r++) {
        int gi = r0 + r;
        if (gi < M) {
            if (OMODE == 2) {
                ((unsigned short*)outv)[(size_t)gi * 256 + pj0] = f2bf(acc0[r]);
                ((unsigned short*)outv)[(size_t)gi * 256 + pj1] = f2bf(acc1[r]);
            } else {
                ((float*)outv)[(size_t)gi * 256 + pj0] = acc0[r];
                ((float*)outv)[(size_t)gi * 256 + pj1] = acc1[r];
            }
        }
    }
}

// WA[k][j] = lin_w[k][j] + lin_w[k+256][j]
__global__ __launch_bounds__(256) void k_wa(const float* __restrict__ lw, float* __restrict__ WA) {
    int i = blockIdx.x * 256 + threadIdx.x;   // 0..32767
    WA[i] = lw[i] + lw[i + 256 * 256];
}

// ---------------- edge CSR build ----------------
__global__ __launch_bounds__(256) void k_hist(const int* __restrict__ idx0, int* __restrict__ hist, int E) {
    int e = blockIdx.x * 256 + threadIdx.x;
    if (e < E) atomicAdd(&hist[idx0[e]], 1);
}

__global__ __launch_bounds__(256) void k_scan1(const int* __restrict__ hist, int* __restrict__ incl,
                                               int* __restrict__ bsum, int N) {
    __shared__ int s[256];
    int i = blockIdx.x * 256 + threadIdx.x;
    int v = (i < N) ? hist[i] : 0;
    s[threadIdx.x] = v;
    __syncthreads();
    for (int ofs = 1; ofs < 256; ofs <<= 1) {
        int t = (threadIdx.x >= ofs) ? s[threadIdx.x - ofs] : 0;
        __syncthreads();
        s[threadIdx.x] += t;
        __syncthreads();
    }
    if (i < N) incl[i] = s[threadIdx.x];          // written at rowptr+1
    if (threadIdx.x == 255) bsum[blockIdx.x] = s[255];
}

__global__ __launch_bounds__(256) void k_scan2(const int* __restrict__ bsum, int* __restrict__ bofs, int nb) {
    __shared__ int s[256];
    int v = (threadIdx.x < nb) ? bsum[threadIdx.x] : 0;
    s[threadIdx.x] = v;
    __syncthreads();
    for (int ofs = 1; ofs < 256; ofs <<= 1) {
        int t = (threadIdx.x >= ofs) ? s[threadIdx.x - ofs] : 0;
        __syncthreads();
        s[threadIdx.x] += t;
        __syncthreads();
    }
    if (threadIdx.x < nb) bofs[threadIdx.x] = s[threadIdx.x] - v;  // exclusive
}

__global__ __launch_bounds__(256) void k_scan3(int* __restrict__ rowptr, const int* __restrict__ bofs, int N) {
    int i = blockIdx.x * 256 + threadIdx.x;
    if (i < N) rowptr[i + 1] += bofs[blockIdx.x];
    if (i == 0 && blockIdx.x == 0) rowptr[0] = 0;
}

// scatter sidx1 in CSR order; also histogram idx1 -> cnt1 (for dense C stats)
__global__ __launch_bounds__(256) void k_scatter(const int* __restrict__ idx0, const int* __restrict__ idx1,
                                                 const int* __restrict__ rowptr, int* __restrict__ fill,
                                                 int* __restrict__ sidx1, int* __restrict__ cnt1, int E) {
    int e = blockIdx.x * 256 + threadIdx.x;
    if (e < E) {
        int n = idx0[e];
        int m = idx1[e];
        int pos = rowptr[n] + atomicAdd(&fill[n], 1);
        sidx1[pos] = m;
        atomicAdd(&cnt1[m], 1);
    }
}

// ---------------- graph CSR build (nodes sorted by batch) ----------------
__global__ __launch_bounds__(128) void k_gcount(const int* __restrict__ batch, int* __restrict__ gcount, int N) {
    int n = blockIdx.x * 128 + threadIdx.x;
    if (n < N) atomicAdd(&gcount[batch[n]], 1);
}

__global__ __launch_bounds__(128) void k_gscan(const int* __restrict__ gcount, int* __restrict__ gptr) {
    __shared__ int s[128];
    int t = threadIdx.x;
    s[t] = gcount[t];
    __syncthreads();
    for (int ofs = 1; ofs < 128; ofs <<= 1) {
        int v = (t >= ofs) ? s[t - ofs] : 0;
        __syncthreads();
        s[t] += v;
        __syncthreads();
    }
    gptr[t + 1] = s[t];
    if (t == 0) gptr[0] = 0;
}

__global__ __launch_bounds__(128) void k_gscatter(const int* __restrict__ batch, const int* __restrict__ gptr,
                                                  int* __restrict__ gfill, int* __restrict__ gnodes, int N) {
    int n = blockIdx.x * 128 + threadIdx.x;
    if (n < N) {
        int g = batch[n];
        int pos = gptr[g] + atomicAdd(&gfill[g], 1);
        gnodes[pos] = n;
    }
}

// ---------------- BN1 dense stats: sum deg*A, deg*A^2 (packed channel t) ----------------
__global__ __launch_bounds__(256) void k_astat(const float* __restrict__ Apk, const int* __restrict__ rowptr,
                                               float* __restrict__ gsA, float* __restrict__ gqA, int N) {
    __shared__ int rp[65];
    const int t = threadIdx.x;
    const int n0 = blockIdx.x * 64;
    const int nn = min(64, N - n0);
    if (t <= nn) rp[t] = rowptr[n0 + t];
    __syncthreads();
    float sa = 0.f, sq = 0.f;
    for (int i = 0; i < nn; i++) {
        float a = Apk[(size_t)(n0 + i) * 256 + t];
        float deg = (float)(rp[i + 1] - rp[i]);
        sa = fmaf(deg, a, sa);
        sq = fmaf(deg * a, a, sq);
    }
    atomicAdd(&gsA[t], sa);
    atomicAdd(&gqA[t], sq);
}

// ---------------- BN1 dense stats: sum cnt1*C, cnt1*C^2 (packed channel t) ----------------
__global__ __launch_bounds__(256) void k_cstat(const unsigned short* __restrict__ C16, const int* __restrict__ cnt1,
                                               float* __restrict__ gsC, float* __restrict__ gqC, int NHE) {
    __shared__ int ct[64];
    const int t = threadIdx.x;
    const int m0 = blockIdx.x * 64;
    const int mm = min(64, NHE - m0);
    if (t < mm) ct[t] = cnt1[m0 + t];
    __syncthreads();
    float sc = 0.f, sq = 0.f;
    for (int i = 0; i < mm; i++) {
        float c = bfu16(C16[(size_t)(m0 + i) * 256 + t]);
        float w = (float)ct[i];
        sc = fmaf(w, c, sc);
        sq = fmaf(w * c, c, sq);
    }
    atomicAdd(&gsC[t], sc);
    atomicAdd(&gqC[t], sq);
}

// ---------------- BN1 cross term: sum_n A[n] . S[n], S[n] = sum_{e in n} C[m_e] ----------------
// node-parallel: 4 waves/block, 1 node/wave; branch-free inner loop + prefetch
__global__ __launch_bounds__(256) void k_cross(const float* __restrict__ Apk, const uint2* __restrict__ Cpk,
                                               const int* __restrict__ rowptr, const int* __restrict__ sidx1,
                                               float* __restrict__ gcross, int N) {
    __shared__ float4 lcr[256];
    const int t = threadIdx.x;
    const int s = t >> 6, l = t & 63;
    const int n = blockIdx.x * 4 + s;
    float4 cr = {0.f, 0.f, 0.f, 0.f};
    if (n < N) {
        const float4 a = ((const float4*)Apk)[(size_t)n * 64 + l];
        const int e0 = rowptr[n], e1 = rowptr[n + 1];
        float4 csr = {0.f, 0.f, 0.f, 0.f};
        uint2 pnext = {0u, 0u};
        if (e0 < e1) pnext = Cpk[(size_t)sidx1[e0] * 64 + l];
        for (int e = e0; e < e1; e++) {
            uint2 p = pnext;
            if (e + 1 < e1) pnext = Cpk[(size_t)sidx1[e + 1] * 64 + l];
            csr.x += bflo(p.x); csr.y += bfhi(p.x);
            csr.z += bflo(p.y); csr.w += bfhi(p.y);
        }
        cr.x = a.x * csr.x; cr.y = a.y * csr.y;
        cr.z = a.z * csr.z; cr.w = a.w * csr.w;
    }
    lcr[t] = cr;
    __syncthreads();
    const float* fc = (const float*)lcr;
    float v = fc[t] + fc[256 + t] + fc[512 + t] + fc[768 + t];
    atomicAdd(&gcross[t], v);
}

// combine stats; packed j -> original channel; writes packed scale/shift
__global__ __launch_bounds__(256) void k_bn1fin(const float* __restrict__ gsA, const float* __restrict__ gqA,
                                                const float* __restrict__ gsC, const float* __restrict__ gqC,
                                                const float* __restrict__ gcross,
                                                const float* __restrict__ g, const float* __restrict__ b,
                                                float* __restrict__ scale, float* __restrict__ shift, float invE) {
    int j = threadIdx.x;  // packed index
    int l = j >> 2, k = j & 3;
    int ch = (k < 2) ? (2 * l + k) : (128 + 2 * l + (k - 2));
    float sum = gsA[j] + gsC[j];
    float sq  = gqA[j] + gqC[j] + 2.f * gcross[j];
    float mu = sum * invE;
    float var = sq * invE - mu * mu;
    float sc = g[ch] * rsqrtf(var + EPS_BN);
    scale[j] = sc;
    shift[j] = fmaf(-mu, sc, b[ch]);
}

// ---------------- fused msg + segment softmax aggregation (2 waves/block, 1 node/wave) ----------------
// log2e folded into per-node constants -> raw exp2/log2 transcendentals.
__global__ __launch_bounds__(128) void k_aggr(const float* __restrict__ Apk, const uint2* __restrict__ Cpk,
                                              const int* __restrict__ rowptr, const int* __restrict__ sidx1,
                                              const float* __restrict__ scale_pk, const float* __restrict__ shift_pk,
                                              const float* __restrict__ tptr, float* __restrict__ out, int N) {
    const int n = blockIdx.x * 2 + (threadIdx.x >> 6);
    if (n >= N) return;
    const int l = threadIdx.x & 63;
    const float t2 = tptr[0] * LOG2E;
    const float4 sc = ((const float4*)scale_pk)[l];
    const float4 sh = ((const float4*)shift_pk)[l];
    const float4 ap = ((const float4*)Apk)[(size_t)n * 64 + l];
    // sigmoid channels (x,y): -zf*log2e = C*(-sc*log2e) + (-(ap*sc+sh)*log2e)
    const float sfx = -sc.x * LOG2E, sfy = -sc.y * LOG2E;
    const float bfx = -fmaf(ap.x, sc.x, sh.x) * LOG2E;
    const float bfy = -fmaf(ap.y, sc.y, sh.y) * LOG2E;
    // softplus channels (z,w): zc*log2e
    const float scz = sc.z * LOG2E, scw = sc.w * LOG2E;
    const float bcz = fmaf(ap.z, sc.z, sh.z) * LOG2E;
    const float bcw = fmaf(ap.w, sc.w, sh.w) * LOG2E;
    const int e0 = rowptr[n], e1 = rowptr[n + 1];
    float den0 = 0.f, num0 = 0.f, den1 = 0.f, num1 = 0.f;
    uint2 pnext = {0u, 0u};
    if (e0 < e1) pnext = Cpk[(size_t)sidx1[e0] * 64 + l];
    for (int e = e0; e < e1; e++) {
        uint2 p = pnext;
        if (e + 1 < e1) pnext = Cpk[(size_t)sidx1[e + 1] * 64 + l];
        float ef0 = fexp2(fmaf(bflo(p.x), sfx, bfx));       // e^{-zf0}
        float ef1 = fexp2(fmaf(bfhi(p.x), sfy, bfy));
        float u0  = fexp2(fmaf(bflo(p.y), scz, bcz));       // e^{zc0}
        float u1  = fexp2(fmaf(bfhi(p.y), scw, bcw));
        float sig0 = __builtin_amdgcn_rcpf(1.f + ef0);
        float sig1 = __builtin_amdgcn_rcpf(1.f + ef1);
        float sp0 = LN2 * flog2(1.f + u0);                  // softplus(zc0)
        float sp1 = LN2 * flog2(1.f + u1);
        float msg0 = sig0 * sp0;
        float msg1 = sig1 * sp1;
        float w0 = fexp2(t2 * msg0);                        // e^{t*msg0}
        float w1 = fexp2(t2 * msg1);
        den0 += w0; num0 = fmaf(msg0, w0, num0);
        den1 += w1; num1 = fmaf(msg1, w1, num1);
    }
    float2 o;
    o.x = (e1 > e0) ? num0 / den0 : 0.f;
    o.y = (e1 > e0) ? num1 / den1 : 0.f;
    ((float2*)out)[(size_t)n * 64 + l] = o;    // channels 2l, 2l+1 (natural order)
}

// ---------------- BN2 ----------------
__global__ __launch_bounds__(128) void k_bn2stats(const float* __restrict__ out, float* __restrict__ sum,
                                                  float* __restrict__ sq, int N) {
    const int c = threadIdx.x;  // 128
    const int n0 = blockIdx.x * 64;
    const int nend = min(n0 + 64, N);
    float sm = 0.f, s2 = 0.f;
    for (int n = n0; n < nend; n++) {
        float v = out[(size_t)n * 128 + c];
        sm += v;
        s2 = fmaf(v, v, s2);
    }
    atomicAdd(&sum[c], sm);
    atomicAdd(&sq[c], s2);
}

__global__ __launch_bounds__(128) void k_bn2fin(const float* __restrict__ sum, const float* __restrict__ sq,
                                                const float* __restrict__ g, const float* __restrict__ b,
                                                float* __restrict__ scale, float* __restrict__ shift, float invN) {
    int j = threadIdx.x;  // 128
    float mu = sum[j] * invN;
    float var = sq[j] * invN - mu * mu;
    float sc = g[j] * rsqrtf(var + EPS_BN);
    scale[j] = sc;
    shift[j] = fmaf(-mu, sc, b[j]);
}

// ---------------- residual+softplus + mean-pool (batch-CSR, register accum, no LDS) ----------------
template<int SPLIT>
__global__ __launch_bounds__(128) void k_h2pool(const float* __restrict__ out, const float* __restrict__ h,
                                                const int* __restrict__ gptr, const int* __restrict__ gnodes,
                                                const float* __restrict__ scale, const float* __restrict__ shift,
                                                float* __restrict__ pooled) {
    const int g = blockIdx.x & 127;
    const int sp = blockIdx.x >> 7;
    const int c = threadIdx.x;                 // 128
    const float sc = scale[c], sh = shift[c];
    const int i0 = gptr[g], i1 = gptr[g + 1];
    float acc = 0.f;
    for (int i = i0 + sp; i < i1; i += SPLIT) {
        int n = gnodes[i];
        float v = fmaf(out[(size_t)n * 128 + c], sc, sh) + h[(size_t)n * 128 + c];
        acc += softplus_fast(v);
    }
    if (acc != 0.f) atomicAdd(&pooled[g * 128 + c], acc);
}

// ---------------- head ----------------
__global__ __launch_bounds__(256) void k_head(const float* __restrict__ pooled, const int* __restrict__ gcount,
                                              const float* __restrict__ l1w, const float* __restrict__ l1b,
                                              const float* __restrict__ outw, const float* __restrict__ outb,
                                              float* __restrict__ dout) {
    __shared__ float p[128];
    __shared__ float red[256];
    const int g = blockIdx.x;
    const int j = threadIdx.x;  // 256
    if (j < 128) {
        float cnt = (float)max(gcount[g], 1);
        p[j] = pooled[g * 128 + j] / cnt;
    }
    __syncthreads();
    float acc = l1b[j];
    for (int k = 0; k < 128; k++) acc = fmaf(p[k], l1w[k * 256 + j], acc);
    red[j] = softplus_fast(acc) * outw[j];
    __syncthreads();
    for (int s = 128; s > 0; s >>= 1) {
        if (j < s) red[j] += red[j + s];
        __syncthreads();
    }
    if (j == 0) dout[g] = red[0] + outb[0];
}

// ---------------- launch ----------------
extern "C" void kernel_launch(void* const* d_in, const int* in_sizes, int n_in,
                              void* d_out, int out_size, void* d_ws, size_t ws_size,
                              hipStream_t stream) {
    const float* x        = (const float*)d_in[0];
    const float* hedge    = (const float*)d_in[1];
    const int*   iri      = (const int*)d_in[2];
    const int*   batch    = (const int*)d_in[3];
    const float* embed_w  = (const float*)d_in[5];
    const float* embed_b  = (const float*)d_in[6];
    const float* bembed_w = (const float*)d_in[7];
    const float* bembed_b = (const float*)d_in[8];
    const float* lin_w    = (const float*)d_in[9];
    const float* lin_b    = (const float*)d_in[10];
    const float* bn1_g    = (const float*)d_in[11];
    const float* bn1_b    = (const float*)d_in[12];
    const float* bn2_g    = (const float*)d_in[13];
    const float* bn2_b    = (const float*)d_in[14];
    const float* aggr_t   = (const float*)d_in[15];
    const float* l1_w     = (const float*)d_in[16];
    const float* l1_b     = (const float*)d_in[17];
    const float* out_w    = (const float*)d_in[18];
    const float* out_b    = (const float*)d_in[19];

    const int N   = in_sizes[0] / 92;
    const int NHE = in_sizes[1] / 40;
    const int E   = in_sizes[2] / 3;
    const int* idx0 = iri;
    const int* idx1 = iri + E;

    float* ws = (float*)d_ws;
    size_t off = 0;
    auto alloc = [&](size_t elems) -> float* {
        float* p = ws + off;
        off += (elems + 63) & ~(size_t)63;
        return p;
    };
    float* h      = alloc((size_t)N * 128);
    float* cf     = alloc((size_t)NHE * 128);
    float* Apk    = alloc((size_t)N * 256);        // packed f32
    float* Cpk    = alloc((size_t)NHE * 128);      // packed bf16 (NHE*256 u16)
    float* WA     = alloc(128 * 256);
    int*   rowptr = (int*)alloc((size_t)N + 1);
    int*   sidx1  = (int*)alloc((size_t)E);
    int*   gptr   = (int*)alloc(129);
    int*   gnodes = (int*)alloc((size_t)N);
    int*   bsum   = (int*)alloc(256);
    int*   bofs   = (int*)alloc(256);
    float* bn1_scale = alloc(256);
    float* bn1_shift = alloc(256);
    float* bn2_scale = alloc(128);
    float* bn2_shift = alloc(128);
    float* outbuf = alloc((size_t)N * 128);
    // contiguous zero region
    float* zbase  = ws + off;
    int*   hist   = (int*)alloc((size_t)N);
    int*   fill   = (int*)alloc((size_t)N);
    int*   cnt1   = (int*)alloc((size_t)NHE);
    int*   gfill  = (int*)alloc(128);
    float* gsA    = alloc(256);
    float* gqA    = alloc(256);
    float* gsC    = alloc(256);
    float* gqC    = alloc(256);
    float* gcross = alloc(256);
    float* bn2_sum = alloc(128);
    float* bn2_sq  = alloc(128);
    float* pooled  = alloc(128 * 128);
    int*   gcount  = (int*)alloc(128);
    size_t zbytes = (size_t)((ws + off) - zbase) * sizeof(float);
    (void)ws_size;  // ~160MB; fit verified R1-R7

    hipMemsetAsync(zbase, 0, zbytes, stream);

    // dense precompute
    gemm_rows<92, 16><<<(N + 15) / 16, 128, 0, stream>>>(x, embed_w, embed_b, h, N);
    gemm_rows<40, 16><<<(NHE + 15) / 16, 128, 0, stream>>>(hedge, bembed_w, bembed_b, cf, NHE);
    k_wa<<<128, 256, 0, stream>>>(lin_w, WA);
    gemm_rows2<128, 16, 1><<<(N + 15) / 16, 128, 0, stream>>>(h, WA, lin_b, Apk, N);
    gemm_rows2<128, 16, 2><<<(NHE + 15) / 16, 128, 0, stream>>>(cf, lin_w + 128 * 256, nullptr, Cpk, NHE);

    // edge CSR build (counting sort by idx0); cnt1 histogram fused into scatter
    k_hist<<<(E + 255) / 256, 256, 0, stream>>>(idx0, hist, E);
    int nchunk = (N + 255) / 256;   // 196 <= 256
    k_scan1<<<nchunk, 256, 0, stream>>>(hist, rowptr + 1, bsum, N);
    k_scan2<<<1, 256, 0, stream>>>(bsum, bofs, nchunk);
    k_scan3<<<nchunk, 256, 0, stream>>>(rowptr, bofs, N);
    k_scatter<<<(E + 255) / 256, 256, 0, stream>>>(idx0, idx1, rowptr, fill, sidx1, cnt1, E);

    // graph CSR build (counting sort by batch)
    k_gcount<<<(N + 127) / 128, 128, 0, stream>>>(batch, gcount, N);
    k_gscan<<<1, 128, 0, stream>>>(gcount, gptr);
    k_gscatter<<<(N + 127) / 128, 128, 0, stream>>>(batch, gptr, gfill, gnodes, N);

    // BN1 stats: dense A/C terms + edge cross term
    k_astat<<<(N + 63) / 64, 256, 0, stream>>>(Apk, rowptr, gsA, gqA, N);
    k_cstat<<<(NHE + 63) / 64, 256, 0, stream>>>((const unsigned short*)Cpk, cnt1, gsC, gqC, NHE);
    k_cross<<<(N + 3) / 4, 256, 0, stream>>>(Apk, (const uint2*)Cpk, rowptr, sidx1, gcross, N);
    k_bn1fin<<<1, 256, 0, stream>>>(gsA, gqA, gsC, gqC, gcross, bn1_g, bn1_b, bn1_scale, bn1_shift, 1.0f / (float)E);

    // fused message + softmax aggregation (2 nodes per block)
    k_aggr<<<(N + 1) / 2, 128, 0, stream>>>(Apk, (const uint2*)Cpk, rowptr, sidx1, bn1_scale, bn1_shift, aggr_t, outbuf, N);

    // BN2 + residual/softplus + pool
    k_bn2stats<<<(N + 63) / 64, 128, 0, stream>>>(outbuf, bn2_sum, bn2_sq, N);
    k_bn2fin<<<1, 128, 0, stream>>>(bn2_sum, bn2_sq, bn2_g, bn2_b, bn2_scale, bn2_shift, 1.0f / (float)N);
    k_h2pool<16><<<128 * 16, 128, 0, stream>>>(outbuf, h, gptr, gnodes, bn2_scale, bn2_shift, pooled);

    // head
    k_head<<<128, 256, 0, stream>>>(pooled, gcount, l1_w, l1_b, out_w, out_b, (float*)d_out);
}

// Round 9
// 824.798 us; speedup vs baseline: 1.2241x; 1.2241x over previous
//
#include <hip/hip_runtime.h>
#include <hip/hip_bf16.h>

// CrystalHypergraphConv — MI355X implementation.
//
// Decomposition: z[e] = A[idx0[e]] + C[idx1[e]] where
//   A = h @ (lin_w[0:128]+lin_w[256:384]) + lin_b   [N,256]
//   C = connect_feats @ lin_w[128:256]              [NHE,256]
// C stored bf16-packed; lane l owns channels {2l,2l+1,128+2l,129+2l}.
//
// R8 -> R9: R8's node-parallel k_cross regressed 3x (12.5k blocks -> 3.2M
// atomics on 256 addresses; 16-iter waves). Reverted edge pass to the
// R7-proven chunked shape (2048 blocks x 4 waves x ~98 contiguous edges,
// run-amortized A, 1-deep C prefetch) but computing ONLY the cross term
// (dense k_astat/k_cstat keep the rest of BN1 stats — verified R8).
// GEMMs reverted to exact R7 gemm_rows (proven). k_aggr keeps R8 exp2 form.

#define EPS_BN 1e-5f
#define LOG2E 1.4426950408889634f
#define LN2   0.6931471805599453f

__device__ __forceinline__ float fexp2(float x) {
#if __has_builtin(__builtin_amdgcn_exp2f)
    return __builtin_amdgcn_exp2f(x);
#else
    return __expf(x * LN2);
#endif
}
__device__ __forceinline__ float flog2(float x) {
#if __has_builtin(__builtin_amdgcn_logf)
    return __builtin_amdgcn_logf(x);
#else
    return __logf(x) * LOG2E;
#endif
}
// branch-free softplus; safe for |x| < ~80 (data is BN-normalized, |x|<~10)
__device__ __forceinline__ float softplus_fast(float x) {
    return LN2 * flog2(1.f + fexp2(x * LOG2E));
}

__device__ __forceinline__ unsigned short f2bf(float f) {
    unsigned u = __float_as_uint(f);
    unsigned r = (u + 0x7fffu + ((u >> 16) & 1u)) >> 16;   // RNE
    return (unsigned short)r;
}
__device__ __forceinline__ float bflo(unsigned u) { return __uint_as_float(u << 16); }
__device__ __forceinline__ float bfhi(unsigned u) { return __uint_as_float(u & 0xffff0000u); }
__device__ __forceinline__ float bfu16(unsigned short v) { return __uint_as_float(((unsigned)v) << 16); }

// packed channel permutation for NCOL=256
__device__ __forceinline__ int perm256(int j) {
    return (j < 128) ? ((j >> 1) * 4 + (j & 1)) : (((j - 128) >> 1) * 4 + 2 + (j & 1));
}

// ---------------- dense GEMM: out[M,NCOL] = in[M,K] @ W[K,NCOL] + bias (R7-proven) ----------------
// Row-major LDS (conflict-free fill); broadcast float4 per row per 4-k chunk.
// OMODE: 0 = natural f32, 1 = packed f32 (A), 2 = packed bf16 (C)
template<int K, int NCOL, int ROWS, int OMODE>
__global__ __launch_bounds__(NCOL) void gemm_rows(
    const float* __restrict__ in, const float* __restrict__ W,
    const float* __restrict__ bias, void* __restrict__ outv, int M)
{
    static_assert(K % 4 == 0, "K must be multiple of 4");
    __shared__ __align__(16) float xs[ROWS * K];
    const int j = threadIdx.x;
    const int r0 = blockIdx.x * ROWS;
    for (int i = j; i < ROWS * K; i += NCOL) {
        int r = i / K;
        int kk = i - r * K;
        int gi = r0 + r;
        xs[i] = (gi < M) ? in[(size_t)gi * K + kk] : 0.f;   // consecutive addrs -> no conflicts
    }
    __syncthreads();
    float b = bias ? bias[j] : 0.f;
    float acc[ROWS];
#pragma unroll
    for (int r = 0; r < ROWS; r++) acc[r] = b;
#pragma unroll 2
    for (int k4 = 0; k4 < K / 4; k4++) {
        const float* Wk = W + (size_t)(4 * k4) * NCOL + j;
        float w0 = Wk[0];
        float w1 = Wk[NCOL];
        float w2 = Wk[2 * NCOL];
        float w3 = Wk[3 * NCOL];
#pragma unroll
        for (int r = 0; r < ROWS; r++) {
            float4 xv = *(const float4*)(xs + r * K + 4 * k4);   // wave-broadcast b128
            acc[r] = fmaf(xv.x, w0, acc[r]);
            acc[r] = fmaf(xv.y, w1, acc[r]);
            acc[r] = fmaf(xv.z, w2, acc[r]);
            acc[r] = fmaf(xv.w, w3, acc[r]);
        }
    }
    const int pj = (OMODE && NCOL == 256) ? perm256(j) : j;
#pragma unroll
    for (int r = 0; r < ROWS; r++) {
        int gi = r0 + r;
        if (gi < M) {
            if (OMODE == 2) ((unsigned short*)outv)[(size_t)gi * NCOL + pj] = f2bf(acc[r]);
            else            ((float*)outv)[(size_t)gi * NCOL + pj] = acc[r];
        }
    }
}

// WA[k][j] = lin_w[k][j] + lin_w[k+256][j]
__global__ __launch_bounds__(256) void k_wa(const float* __restrict__ lw, float* __restrict__ WA) {
    int i = blockIdx.x * 256 + threadIdx.x;   // 0..32767
    WA[i] = lw[i] + lw[i + 256 * 256];
}

// ---------------- edge CSR build ----------------
__global__ __launch_bounds__(256) void k_hist(const int* __restrict__ idx0, int* __restrict__ hist, int E) {
    int e = blockIdx.x * 256 + threadIdx.x;
    if (e < E) atomicAdd(&hist[idx0[e]], 1);
}

__global__ __launch_bounds__(256) void k_scan1(const int* __restrict__ hist, int* __restrict__ incl,
                                               int* __restrict__ bsum, int N) {
    __shared__ int s[256];
    int i = blockIdx.x * 256 + threadIdx.x;
    int v = (i < N) ? hist[i] : 0;
    s[threadIdx.x] = v;
    __syncthreads();
    for (int ofs = 1; ofs < 256; ofs <<= 1) {
        int t = (threadIdx.x >= ofs) ? s[threadIdx.x - ofs] : 0;
        __syncthreads();
        s[threadIdx.x] += t;
        __syncthreads();
    }
    if (i < N) incl[i] = s[threadIdx.x];          // written at rowptr+1
    if (threadIdx.x == 255) bsum[blockIdx.x] = s[255];
}

__global__ __launch_bounds__(256) void k_scan2(const int* __restrict__ bsum, int* __restrict__ bofs, int nb) {
    __shared__ int s[256];
    int v = (threadIdx.x < nb) ? bsum[threadIdx.x] : 0;
    s[threadIdx.x] = v;
    __syncthreads();
    for (int ofs = 1; ofs < 256; ofs <<= 1) {
        int t = (threadIdx.x >= ofs) ? s[threadIdx.x - ofs] : 0;
        __syncthreads();
        s[threadIdx.x] += t;
        __syncthreads();
    }
    if (threadIdx.x < nb) bofs[threadIdx.x] = s[threadIdx.x] - v;  // exclusive
}

__global__ __launch_bounds__(256) void k_scan3(int* __restrict__ rowptr, const int* __restrict__ bofs, int N) {
    int i = blockIdx.x * 256 + threadIdx.x;
    if (i < N) rowptr[i + 1] += bofs[blockIdx.x];
    if (i == 0 && blockIdx.x == 0) rowptr[0] = 0;
}

// scatter snode/sidx1 in CSR order; also histogram idx1 -> cnt1 (for dense C stats)
__global__ __launch_bounds__(256) void k_scatter(const int* __restrict__ idx0, const int* __restrict__ idx1,
                                                 const int* __restrict__ rowptr, int* __restrict__ fill,
                                                 int* __restrict__ snode, int* __restrict__ sidx1,
                                                 int* __restrict__ cnt1, int E) {
    int e = blockIdx.x * 256 + threadIdx.x;
    if (e < E) {
        int n = idx0[e];
        int m = idx1[e];
        int pos = rowptr[n] + atomicAdd(&fill[n], 1);
        snode[pos] = n;
        sidx1[pos] = m;
        atomicAdd(&cnt1[m], 1);
    }
}

// ---------------- graph CSR build (nodes sorted by batch) ----------------
__global__ __launch_bounds__(128) void k_gcount(const int* __restrict__ batch, int* __restrict__ gcount, int N) {
    int n = blockIdx.x * 128 + threadIdx.x;
    if (n < N) atomicAdd(&gcount[batch[n]], 1);
}

__global__ __launch_bounds__(128) void k_gscan(const int* __restrict__ gcount, int* __restrict__ gptr) {
    __shared__ int s[128];
    int t = threadIdx.x;
    s[t] = gcount[t];
    __syncthreads();
    for (int ofs = 1; ofs < 128; ofs <<= 1) {
        int v = (t >= ofs) ? s[t - ofs] : 0;
        __syncthreads();
        s[t] += v;
        __syncthreads();
    }
    gptr[t + 1] = s[t];
    if (t == 0) gptr[0] = 0;
}

__global__ __launch_bounds__(128) void k_gscatter(const int* __restrict__ batch, const int* __restrict__ gptr,
                                                  int* __restrict__ gfill, int* __restrict__ gnodes, int N) {
    int n = blockIdx.x * 128 + threadIdx.x;
    if (n < N) {
        int g = batch[n];
        int pos = gptr[g] + atomicAdd(&gfill[g], 1);
        gnodes[pos] = n;
    }
}

// ---------------- BN1 dense stats: sum deg*A, deg*A^2 (packed channel t) [verified R8] ----------------
__global__ __launch_bounds__(256) void k_astat(const float* __restrict__ Apk, const int* __restrict__ rowptr,
                                               float* __restrict__ gsA, float* __restrict__ gqA, int N) {
    __shared__ int rp[65];
    const int t = threadIdx.x;
    const int n0 = blockIdx.x * 64;
    const int nn = min(64, N - n0);
    if (t <= nn) rp[t] = rowptr[n0 + t];
    __syncthreads();
    float sa = 0.f, sq = 0.f;
    for (int i = 0; i < nn; i++) {
        float a = Apk[(size_t)(n0 + i) * 256 + t];
        float deg = (float)(rp[i + 1] - rp[i]);
        sa = fmaf(deg, a, sa);
        sq = fmaf(deg * a, a, sq);
    }
    atomicAdd(&gsA[t], sa);
    atomicAdd(&gqA[t], sq);
}

// ---------------- BN1 dense stats: sum cnt1*C, cnt1*C^2 (packed channel t) [verified R8] ----------------
__global__ __launch_bounds__(256) void k_cstat(const unsigned short* __restrict__ C16, const int* __restrict__ cnt1,
                                               float* __restrict__ gsC, float* __restrict__ gqC, int NHE) {
    __shared__ int ct[64];
    const int t = threadIdx.x;
    const int m0 = blockIdx.x * 64;
    const int mm = min(64, NHE - m0);
    if (t < mm) ct[t] = cnt1[m0 + t];
    __syncthreads();
    float sc = 0.f, sq = 0.f;
    for (int i = 0; i < mm; i++) {
        float c = bfu16(C16[(size_t)(m0 + i) * 256 + t]);
        float w = (float)ct[i];
        sc = fmaf(w, c, sc);
        sq = fmaf(w * c, c, sq);
    }
    atomicAdd(&gsC[t], sc);
    atomicAdd(&gqC[t], sq);
}

// ---------------- BN1 cross term: sum_e A[n_e].C[m_e], chunked R7 shape ----------------
// 2048 blocks x 4 waves, ~98 contiguous CSR edges/wave; run-amortized A;
// per edge: 4 adds (csr += c); per run flush: cross += a*csr (4 fma).
__global__ __launch_bounds__(256) void k_cross(const float* __restrict__ Apk, const uint2* __restrict__ Cpk,
                                               const int* __restrict__ snode, const int* __restrict__ sidx1,
                                               float* __restrict__ gcross, int E, int per_slot) {
    __shared__ float4 lcr[256];
    const int t = threadIdx.x;
    const int s = t >> 6, l = t & 63;
    const float4* A4 = (const float4*)Apk;
    const long base = (long)(blockIdx.x * 4 + s) * per_slot;
    const int e0 = (int)min((long)E, base);
    const int e1 = (int)min((long)E, base + per_slot);
    float4 cross = {0.f, 0.f, 0.f, 0.f};
    float4 csr = {0.f, 0.f, 0.f, 0.f};
    float4 a = {0.f, 0.f, 0.f, 0.f};
    int cur_n = -1;
    uint2 pnext = {0u, 0u};
    if (e0 < e1) pnext = Cpk[(size_t)sidx1[e0] * 64 + l];
    for (int e = e0; e < e1; e++) {
        int n = snode[e];                       // wave-uniform, sequential (cached)
        uint2 p = pnext;
        if (e + 1 < e1) pnext = Cpk[(size_t)sidx1[e + 1] * 64 + l];
        if (n != cur_n) {                       // wave-uniform branch
            cross.x = fmaf(a.x, csr.x, cross.x);
            cross.y = fmaf(a.y, csr.y, cross.y);
            cross.z = fmaf(a.z, csr.z, cross.z);
            cross.w = fmaf(a.w, csr.w, cross.w);
            a = A4[(size_t)n * 64 + l];
            cur_n = n;
            csr.x = 0.f; csr.y = 0.f; csr.z = 0.f; csr.w = 0.f;
        }
        csr.x += bflo(p.x); csr.y += bfhi(p.x);
        csr.z += bflo(p.y); csr.w += bfhi(p.y);
    }
    cross.x = fmaf(a.x, csr.x, cross.x);
    cross.y = fmaf(a.y, csr.y, cross.y);
    cross.z = fmaf(a.z, csr.z, cross.z);
    cross.w = fmaf(a.w, csr.w, cross.w);
    lcr[t] = cross;
    __syncthreads();
    const float* fc = (const float*)lcr;
    float v = fc[t] + fc[256 + t] + fc[512 + t] + fc[768 + t];
    atomicAdd(&gcross[t], v);
}

// combine stats; packed j -> original channel; writes packed scale/shift [verified R8]
__global__ __launch_bounds__(256) void k_bn1fin(const float* __restrict__ gsA, const float* __restrict__ gqA,
                                                const float* __restrict__ gsC, const float* __restrict__ gqC,
                                                const float* __restrict__ gcross,
                                                const float* __restrict__ g, const float* __restrict__ b,
                                                float* __restrict__ scale, float* __restrict__ shift, float invE) {
    int j = threadIdx.x;  // packed index
    int l = j >> 2, k = j & 3;
    int ch = (k < 2) ? (2 * l + k) : (128 + 2 * l + (k - 2));
    float sum = gsA[j] + gsC[j];
    float sq  = gqA[j] + gqC[j] + 2.f * gcross[j];
    float mu = sum * invE;
    float var = sq * invE - mu * mu;
    float sc = g[ch] * rsqrtf(var + EPS_BN);
    scale[j] = sc;
    shift[j] = fmaf(-mu, sc, b[ch]);
}

// ---------------- fused msg + segment softmax aggregation (2 waves/block, 1 node/wave) ----------------
// log2e folded into per-node constants -> raw exp2/log2 transcendentals. [verified R8]
__global__ __launch_bounds__(128) void k_aggr(const float* __restrict__ Apk, const uint2* __restrict__ Cpk,
                                              const int* __restrict__ rowptr, const int* __restrict__ sidx1,
                                              const float* __restrict__ scale_pk, const float* __restrict__ shift_pk,
                                              const float* __restrict__ tptr, float* __restrict__ out, int N) {
    const int n = blockIdx.x * 2 + (threadIdx.x >> 6);
    if (n >= N) return;
    const int l = threadIdx.x & 63;
    const float t2 = tptr[0] * LOG2E;
    const float4 sc = ((const float4*)scale_pk)[l];
    const float4 sh = ((const float4*)shift_pk)[l];
    const float4 ap = ((const float4*)Apk)[(size_t)n * 64 + l];
    const float sfx = -sc.x * LOG2E, sfy = -sc.y * LOG2E;
    const float bfx = -fmaf(ap.x, sc.x, sh.x) * LOG2E;
    const float bfy = -fmaf(ap.y, sc.y, sh.y) * LOG2E;
    const float scz = sc.z * LOG2E, scw = sc.w * LOG2E;
    const float bcz = fmaf(ap.z, sc.z, sh.z) * LOG2E;
    const float bcw = fmaf(ap.w, sc.w, sh.w) * LOG2E;
    const int e0 = rowptr[n], e1 = rowptr[n + 1];
    float den0 = 0.f, num0 = 0.f, den1 = 0.f, num1 = 0.f;
    uint2 pnext = {0u, 0u};
    if (e0 < e1) pnext = Cpk[(size_t)sidx1[e0] * 64 + l];
    for (int e = e0; e < e1; e++) {
        uint2 p = pnext;
        if (e + 1 < e1) pnext = Cpk[(size_t)sidx1[e + 1] * 64 + l];
        float ef0 = fexp2(fmaf(bflo(p.x), sfx, bfx));       // e^{-zf0}
        float ef1 = fexp2(fmaf(bfhi(p.x), sfy, bfy));
        float u0  = fexp2(fmaf(bflo(p.y), scz, bcz));       // e^{zc0}
        float u1  = fexp2(fmaf(bfhi(p.y), scw, bcw));
        float sig0 = __builtin_amdgcn_rcpf(1.f + ef0);
        float sig1 = __builtin_amdgcn_rcpf(1.f + ef1);
        float sp0 = LN2 * flog2(1.f + u0);                  // softplus(zc0)
        float sp1 = LN2 * flog2(1.f + u1);
        float msg0 = sig0 * sp0;
        float msg1 = sig1 * sp1;
        float w0 = fexp2(t2 * msg0);                        // e^{t*msg0}
        float w1 = fexp2(t2 * msg1);
        den0 += w0; num0 = fmaf(msg0, w0, num0);
        den1 += w1; num1 = fmaf(msg1, w1, num1);
    }
    float2 o;
    o.x = (e1 > e0) ? num0 / den0 : 0.f;
    o.y = (e1 > e0) ? num1 / den1 : 0.f;
    ((float2*)out)[(size_t)n * 64 + l] = o;    // channels 2l, 2l+1 (natural order)
}

// ---------------- BN2 ----------------
__global__ __launch_bounds__(128) void k_bn2stats(const float* __restrict__ out, float* __restrict__ sum,
                                                  float* __restrict__ sq, int N) {
    const int c = threadIdx.x;  // 128
    const int n0 = blockIdx.x * 64;
    const int nend = min(n0 + 64, N);
    float sm = 0.f, s2 = 0.f;
    for (int n = n0; n < nend; n++) {
        float v = out[(size_t)n * 128 + c];
        sm += v;
        s2 = fmaf(v, v, s2);
    }
    atomicAdd(&sum[c], sm);
    atomicAdd(&sq[c], s2);
}

__global__ __launch_bounds__(128) void k_bn2fin(const float* __restrict__ sum, const float* __restrict__ sq,
                                                const float* __restrict__ g, const float* __restrict__ b,
                                                float* __restrict__ scale, float* __restrict__ shift, float invN) {
    int j = threadIdx.x;  // 128
    float mu = sum[j] * invN;
    float var = sq[j] * invN - mu * mu;
    float sc = g[j] * rsqrtf(var + EPS_BN);
    scale[j] = sc;
    shift[j] = fmaf(-mu, sc, b[j]);
}

// ---------------- residual+softplus + mean-pool (batch-CSR, register accum, no LDS) ----------------
template<int SPLIT>
__global__ __launch_bounds__(128) void k_h2pool(const float* __restrict__ out, const float* __restrict__ h,
                                                const int* __restrict__ gptr, const int* __restrict__ gnodes,
                                                const float* __restrict__ scale, const float* __restrict__ shift,
                                                float* __restrict__ pooled) {
    const int g = blockIdx.x & 127;
    const int sp = blockIdx.x >> 7;
    const int c = threadIdx.x;                 // 128
    const float sc = scale[c], sh = shift[c];
    const int i0 = gptr[g], i1 = gptr[g + 1];
    float acc = 0.f;
    for (int i = i0 + sp; i < i1; i += SPLIT) {
        int n = gnodes[i];
        float v = fmaf(out[(size_t)n * 128 + c], sc, sh) + h[(size_t)n * 128 + c];
        acc += softplus_fast(v);
    }
    if (acc != 0.f) atomicAdd(&pooled[g * 128 + c], acc);
}

// ---------------- head ----------------
__global__ __launch_bounds__(256) void k_head(const float* __restrict__ pooled, const int* __restrict__ gcount,
                                              const float* __restrict__ l1w, const float* __restrict__ l1b,
                                              const float* __restrict__ outw, const float* __restrict__ outb,
                                              float* __restrict__ dout) {
    __shared__ float p[128];
    __shared__ float red[256];
    const int g = blockIdx.x;
    const int j = threadIdx.x;  // 256
    if (j < 128) {
        float cnt = (float)max(gcount[g], 1);
        p[j] = pooled[g * 128 + j] / cnt;
    }
    __syncthreads();
    float acc = l1b[j];
    for (int k = 0; k < 128; k++) acc = fmaf(p[k], l1w[k * 256 + j], acc);
    red[j] = softplus_fast(acc) * outw[j];
    __syncthreads();
    for (int s = 128; s > 0; s >>= 1) {
        if (j < s) red[j] += red[j + s];
        __syncthreads();
    }
    if (j == 0) dout[g] = red[0] + outb[0];
}

// ---------------- launch ----------------
extern "C" void kernel_launch(void* const* d_in, const int* in_sizes, int n_in,
                              void* d_out, int out_size, void* d_ws, size_t ws_size,
                              hipStream_t stream) {
    const float* x        = (const float*)d_in[0];
    const float* hedge    = (const float*)d_in[1];
    const int*   iri      = (const int*)d_in[2];
    const int*   batch    = (const int*)d_in[3];
    const float* embed_w  = (const float*)d_in[5];
    const float* embed_b  = (const float*)d_in[6];
    const float* bembed_w = (const float*)d_in[7];
    const float* bembed_b = (const float*)d_in[8];
    const float* lin_w    = (const float*)d_in[9];
    const float* lin_b    = (const float*)d_in[10];
    const float* bn1_g    = (const float*)d_in[11];
    const float* bn1_b    = (const float*)d_in[12];
    const float* bn2_g    = (const float*)d_in[13];
    const float* bn2_b    = (const float*)d_in[14];
    const float* aggr_t   = (const float*)d_in[15];
    const float* l1_w     = (const float*)d_in[16];
    const float* l1_b     = (const float*)d_in[17];
    const float* out_w    = (const float*)d_in[18];
    const float* out_b    = (const float*)d_in[19];

    const int N   = in_sizes[0] / 92;
    const int NHE = in_sizes[1] / 40;
    const int E   = in_sizes[2] / 3;
    const int* idx0 = iri;
    const int* idx1 = iri + E;

    float* ws = (float*)d_ws;
    size_t off = 0;
    auto alloc = [&](size_t elems) -> float* {
        float* p = ws + off;
        off += (elems + 63) & ~(size_t)63;
        return p;
    };
    float* h      = alloc((size_t)N * 128);
    float* cf     = alloc((size_t)NHE * 128);
    float* Apk    = alloc((size_t)N * 256);        // packed f32
    float* Cpk    = alloc((size_t)NHE * 128);      // packed bf16 (NHE*256 u16)
    float* WA     = alloc(128 * 256);
    int*   rowptr = (int*)alloc((size_t)N + 1);
    int*   snode  = (int*)alloc((size_t)E);
    int*   sidx1  = (int*)alloc((size_t)E);
    int*   gptr   = (int*)alloc(129);
    int*   gnodes = (int*)alloc((size_t)N);
    int*   bsum   = (int*)alloc(256);
    int*   bofs   = (int*)alloc(256);
    float* bn1_scale = alloc(256);
    float* bn1_shift = alloc(256);
    float* bn2_scale = alloc(128);
    float* bn2_shift = alloc(128);
    float* outbuf = alloc((size_t)N * 128);
    // contiguous zero region
    float* zbase  = ws + off;
    int*   hist   = (int*)alloc((size_t)N);
    int*   fill   = (int*)alloc((size_t)N);
    int*   cnt1   = (int*)alloc((size_t)NHE);
    int*   gfill  = (int*)alloc(128);
    float* gsA    = alloc(256);
    float* gqA    = alloc(256);
    float* gsC    = alloc(256);
    float* gqC    = alloc(256);
    float* gcross = alloc(256);
    float* bn2_sum = alloc(128);
    float* bn2_sq  = alloc(128);
    float* pooled  = alloc(128 * 128);
    int*   gcount  = (int*)alloc(128);
    size_t zbytes = (size_t)((ws + off) - zbase) * sizeof(float);
    (void)ws_size;  // ~160MB; fit verified R1-R8

    hipMemsetAsync(zbase, 0, zbytes, stream);

    // dense precompute (R7-proven config)
    gemm_rows<92, 128, 16, 0><<<(N + 15) / 16, 128, 0, stream>>>(x, embed_w, embed_b, h, N);
    gemm_rows<40, 128, 16, 0><<<(NHE + 15) / 16, 128, 0, stream>>>(hedge, bembed_w, bembed_b, cf, NHE);
    k_wa<<<128, 256, 0, stream>>>(lin_w, WA);
    gemm_rows<128, 256, 16, 1><<<(N + 15) / 16, 256, 0, stream>>>(h, WA, lin_b, Apk, N);
    gemm_rows<128, 256, 16, 2><<<(NHE + 15) / 16, 256, 0, stream>>>(cf, lin_w + 128 * 256, nullptr, Cpk, NHE);

    // edge CSR build (counting sort by idx0); cnt1 histogram fused into scatter
    k_hist<<<(E + 255) / 256, 256, 0, stream>>>(idx0, hist, E);
    int nchunk = (N + 255) / 256;   // 196 <= 256
    k_scan1<<<nchunk, 256, 0, stream>>>(hist, rowptr + 1, bsum, N);
    k_scan2<<<1, 256, 0, stream>>>(bsum, bofs, nchunk);
    k_scan3<<<nchunk, 256, 0, stream>>>(rowptr, bofs, N);
    k_scatter<<<(E + 255) / 256, 256, 0, stream>>>(idx0, idx1, rowptr, fill, snode, sidx1, cnt1, E);

    // graph CSR build (counting sort by batch)
    k_gcount<<<(N + 127) / 128, 128, 0, stream>>>(batch, gcount, N);
    k_gscan<<<1, 128, 0, stream>>>(gcount, gptr);
    k_gscatter<<<(N + 127) / 128, 128, 0, stream>>>(batch, gptr, gfill, gnodes, N);

    // BN1 stats: dense A/C terms + chunked edge cross term
    k_astat<<<(N + 63) / 64, 256, 0, stream>>>(Apk, rowptr, gsA, gqA, N);
    k_cstat<<<(NHE + 63) / 64, 256, 0, stream>>>((const unsigned short*)Cpk, cnt1, gsC, gqC, NHE);
    const int CROSS_BLOCKS = 2048;              // x4 waves = 8192 slots (R7-proven)
    int per_slot = (E + CROSS_BLOCKS * 4 - 1) / (CROSS_BLOCKS * 4);
    k_cross<<<CROSS_BLOCKS, 256, 0, stream>>>(Apk, (const uint2*)Cpk, snode, sidx1, gcross, E, per_slot);
    k_bn1fin<<<1, 256, 0, stream>>>(gsA, gqA, gsC, gqC, gcross, bn1_g, bn1_b, bn1_scale, bn1_shift, 1.0f / (float)E);

    // fused message + softmax aggregation (2 nodes per block)
    k_aggr<<<(N + 1) / 2, 128, 0, stream>>>(Apk, (const uint2*)Cpk, rowptr, sidx1, bn1_scale, bn1_shift, aggr_t, outbuf, N);

    // BN2 + residual/softplus + pool
    k_bn2stats<<<(N + 63) / 64, 128, 0, stream>>>(outbuf, bn2_sum, bn2_sq, N);
    k_bn2fin<<<1, 128, 0, stream>>>(bn2_sum, bn2_sq, bn2_g, bn2_b, bn2_scale, bn2_shift, 1.0f / (float)N);
    k_h2pool<16><<<128 * 16, 128, 0, stream>>>(outbuf, h, gptr, gnodes, bn2_scale, bn2_shift, pooled);

    // head
    k_head<<<128, 256, 0, stream>>>(pooled, gcount, l1_w, l1_b, out_w, out_b, (float*)d_out);
}

// Round 10
// 687.947 us; speedup vs baseline: 1.4676x; 1.1989x over previous
//
#include <hip/hip_runtime.h>
#include <hip/hip_bf16.h>

// CrystalHypergraphConv — MI355X implementation.
//
// Decomposition: z[e] = A[idx0[e]] + C[idx1[e]] where
//   A = h @ (lin_w[0:128]+lin_w[256:384]) + lin_b   [N,256]
//   C = connect_feats @ lin_w[128:256]              [NHE,256]
// C stored bf16-packed; lane l owns channels {2l,2l+1,128+2l,129+2l}.
//
// R9 -> R10:
//  * Edge-pass verdict: k_cross (4 adds/edge) == R7 k_stats (full math) == ~120us
//    -> pass is gather-chain-bound, not VALU-bound. Dropped the R8/R9 stats
//    decomposition (its extra kernels cost ~60us); reverted to R7 single-pass
//    run-amortized k_stats.
//  * GEMMs were the hidden mid-tier: VALU gemm issues 6.4M ds_read_b128
//    (~125us/launch LDS-issue-bound). Rewritten as bf16 MFMA (16x16x32):
//    32-row A tile staged f32->bf16 in LDS frag-major (64 consecutive b128
//    per wave, conflict-free), B-frags in registers, 8 mfma/wave.
//    Layouts per verified guide: A[m=l&15][k=(l>>4)*8+j], C/D col=l&15,
//    row=(l>>4)*4+reg. bf16 weights precomputed by k_prepw.
//  * k_aggr keeps R8/R9 exp2 form.

#define EPS_BN 1e-5f
#define LOG2E 1.4426950408889634f
#define LN2   0.6931471805599453f

typedef __attribute__((ext_vector_type(8))) short bf16x8;
typedef __attribute__((ext_vector_type(4))) float f32x4;

__device__ __forceinline__ float fexp2(float x) {
#if __has_builtin(__builtin_amdgcn_exp2f)
    return __builtin_amdgcn_exp2f(x);
#else
    return __expf(x * LN2);
#endif
}
__device__ __forceinline__ float flog2(float x) {
#if __has_builtin(__builtin_amdgcn_logf)
    return __builtin_amdgcn_logf(x);
#else
    return __logf(x) * LOG2E;
#endif
}
__device__ __forceinline__ float softplus_fast(float x) {
    return LN2 * flog2(1.f + fexp2(x * LOG2E));
}

__device__ __forceinline__ unsigned short f2bf(float f) {
    unsigned u = __float_as_uint(f);
    unsigned r = (u + 0x7fffu + ((u >> 16) & 1u)) >> 16;   // RNE
    return (unsigned short)r;
}
__device__ __forceinline__ float bflo(unsigned u) { return __uint_as_float(u << 16); }
__device__ __forceinline__ float bfhi(unsigned u) { return __uint_as_float(u & 0xffff0000u); }

// packed channel permutation for NCOL=256
__device__ __forceinline__ int perm256(int j) {
    return (j < 128) ? ((j >> 1) * 4 + (j & 1)) : (((j - 128) >> 1) * 4 + 2 + (j & 1));
}

// ---------------- weight prep: bf16 copies (zero-padded K to 128) ----------------
__global__ __launch_bounds__(256) void k_prepw(const float* __restrict__ ew, const float* __restrict__ bw,
                                               const float* __restrict__ lw,
                                               unsigned short* __restrict__ embB, unsigned short* __restrict__ bembB,
                                               unsigned short* __restrict__ waB, unsigned short* __restrict__ wcB) {
    int i = blockIdx.x * 256 + threadIdx.x;          // 0..98303
    if (i < 16384) {                                 // embB [128x128], K=92 padded
        int k = i >> 7, nn = i & 127;
        embB[i] = f2bf(k < 92 ? ew[k * 128 + nn] : 0.f);
    } else if (i < 32768) {                          // bembB [128x128], K=40 padded
        int j = i - 16384;
        int k = j >> 7, nn = j & 127;
        bembB[j] = f2bf(k < 40 ? bw[k * 128 + nn] : 0.f);
    } else if (i < 65536) {                          // waB [128x256] = lw[0:128]+lw[256:384]
        int j = i - 32768;
        waB[j] = f2bf(lw[j] + lw[j + 65536]);
    } else {                                         // wcB [128x256] = lw[128:256]
        int j = i - 65536;
        wcB[j] = f2bf(lw[j + 32768]);
    }
}

// ---------------- MFMA GEMM: out[M,NCOL] = bf16(in[M,KIN]) @ Wb[128,NCOL] + bias ----------------
// block = 256 thr = 4 waves; 32 rows/block; wave w owns cols g*64+w*16 .. +15.
// OMODE: 0 natural f32 [M x NCOL]; 1 packed f32 (NCOL=256); 2 packed bf16 (NCOL=256)
template<int KIN, int NCOL, int OMODE>
__global__ __launch_bounds__(256) void mfma_gemm(
    const float* __restrict__ in, const unsigned short* __restrict__ Wb,
    const float* __restrict__ bias, void* __restrict__ outv, int M)
{
    const int ngrp = NCOL / 64;
    const int mb = blockIdx.x / ngrp;
    const int g  = blockIdx.x % ngrp;
    const int r0 = mb * 32;
    const int t = threadIdx.x;
    const int w = t >> 6;
    const int l = t & 63;
    const int m = l & 15, q = l >> 4;
    const int n = g * 64 + w * 16 + m;               // this lane's output column

    __shared__ __align__(16) unsigned short als[4096];   // [half][c*4+quad][m][j]

    // stage A: 32 rows x 128 k, f32 -> bf16, frag-major layout
    for (int it = 0; it < 16; it++) {
        int i = it * 256 + t;                        // 0..4095
        int r = i >> 7, k = i & 127;
        int gr = r0 + r;
        float v = (gr < M && k < KIN) ? in[(size_t)gr * KIN + k] : 0.f;
        int idx = (r >> 4) * 2048 + (((k >> 5) * 4 + ((k >> 3) & 3)) * 16 + (r & 15)) * 8 + (k & 7);
        als[idx] = f2bf(v);
    }

    // B frags: 4 k-chunks x 8 bf16 per lane (held in registers; W table is L2-hot)
    bf16x8 bf[4];
#pragma unroll
    for (int c = 0; c < 4; c++) {
#pragma unroll
        for (int j = 0; j < 8; j++) {
            int k = c * 32 + q * 8 + j;
            bf[c][j] = (short)Wb[(size_t)k * NCOL + n];
        }
    }
    __syncthreads();

    f32x4 acc0 = {0.f, 0.f, 0.f, 0.f}, acc1 = {0.f, 0.f, 0.f, 0.f};
    const bf16x8* af = (const bf16x8*)als;           // frag index: half*256 + c*64 + l
#pragma unroll
    for (int c = 0; c < 4; c++) {
        bf16x8 a0 = af[c * 64 + l];                  // rows r0..r0+15
        bf16x8 a1 = af[256 + c * 64 + l];            // rows r0+16..r0+31
        acc0 = __builtin_amdgcn_mfma_f32_16x16x32_bf16(a0, bf[c], acc0, 0, 0, 0);
        acc1 = __builtin_amdgcn_mfma_f32_16x16x32_bf16(a1, bf[c], acc1, 0, 0, 0);
    }

    float bv = bias ? bias[n] : 0.f;
    const int pj = (OMODE != 0) ? perm256(n) : n;
#pragma unroll
    for (int h = 0; h < 2; h++) {
        f32x4 acc = h ? acc1 : acc0;
#pragma unroll
        for (int r = 0; r < 4; r++) {
            int row = r0 + h * 16 + q * 4 + r;
            if (row < M) {
                float val = acc[r] + bv;
                if (OMODE == 0)      ((float*)outv)[(size_t)row * NCOL + n] = val;
                else if (OMODE == 1) ((float*)outv)[(size_t)row * 256 + pj] = val;
                else                 ((unsigned short*)outv)[(size_t)row * 256 + pj] = f2bf(val);
            }
        }
    }
}

// ---------------- edge CSR build ----------------
__global__ __launch_bounds__(256) void k_hist(const int* __restrict__ idx0, int* __restrict__ hist, int E) {
    int e = blockIdx.x * 256 + threadIdx.x;
    if (e < E) atomicAdd(&hist[idx0[e]], 1);
}

__global__ __launch_bounds__(256) void k_scan1(const int* __restrict__ hist, int* __restrict__ incl,
                                               int* __restrict__ bsum, int N) {
    __shared__ int s[256];
    int i = blockIdx.x * 256 + threadIdx.x;
    int v = (i < N) ? hist[i] : 0;
    s[threadIdx.x] = v;
    __syncthreads();
    for (int ofs = 1; ofs < 256; ofs <<= 1) {
        int t = (threadIdx.x >= ofs) ? s[threadIdx.x - ofs] : 0;
        __syncthreads();
        s[threadIdx.x] += t;
        __syncthreads();
    }
    if (i < N) incl[i] = s[threadIdx.x];
    if (threadIdx.x == 255) bsum[blockIdx.x] = s[255];
}

__global__ __launch_bounds__(256) void k_scan2(const int* __restrict__ bsum, int* __restrict__ bofs, int nb) {
    __shared__ int s[256];
    int v = (threadIdx.x < nb) ? bsum[threadIdx.x] : 0;
    s[threadIdx.x] = v;
    __syncthreads();
    for (int ofs = 1; ofs < 256; ofs <<= 1) {
        int t = (threadIdx.x >= ofs) ? s[threadIdx.x - ofs] : 0;
        __syncthreads();
        s[threadIdx.x] += t;
        __syncthreads();
    }
    if (threadIdx.x < nb) bofs[threadIdx.x] = s[threadIdx.x] - v;
}

__global__ __launch_bounds__(256) void k_scan3(int* __restrict__ rowptr, const int* __restrict__ bofs, int N) {
    int i = blockIdx.x * 256 + threadIdx.x;
    if (i < N) rowptr[i + 1] += bofs[blockIdx.x];
    if (i == 0 && blockIdx.x == 0) rowptr[0] = 0;
}

__global__ __launch_bounds__(256) void k_scatter(const int* __restrict__ idx0, const int* __restrict__ idx1,
                                                 const int* __restrict__ rowptr, int* __restrict__ fill,
                                                 int* __restrict__ snode, int* __restrict__ sidx1, int E) {
    int e = blockIdx.x * 256 + threadIdx.x;
    if (e < E) {
        int n = idx0[e];
        int pos = rowptr[n] + atomicAdd(&fill[n], 1);
        snode[pos] = n;
        sidx1[pos] = idx1[e];
    }
}

// ---------------- graph CSR build ----------------
__global__ __launch_bounds__(128) void k_gcount(const int* __restrict__ batch, int* __restrict__ gcount, int N) {
    int n = blockIdx.x * 128 + threadIdx.x;
    if (n < N) atomicAdd(&gcount[batch[n]], 1);
}

__global__ __launch_bounds__(128) void k_gscan(const int* __restrict__ gcount, int* __restrict__ gptr) {
    __shared__ int s[128];
    int t = threadIdx.x;
    s[t] = gcount[t];
    __syncthreads();
    for (int ofs = 1; ofs < 128; ofs <<= 1) {
        int v = (t >= ofs) ? s[t - ofs] : 0;
        __syncthreads();
        s[t] += v;
        __syncthreads();
    }
    gptr[t + 1] = s[t];
    if (t == 0) gptr[0] = 0;
}

__global__ __launch_bounds__(128) void k_gscatter(const int* __restrict__ batch, const int* __restrict__ gptr,
                                                  int* __restrict__ gfill, int* __restrict__ gnodes, int N) {
    int n = blockIdx.x * 128 + threadIdx.x;
    if (n < N) {
        int g = batch[n];
        int pos = gptr[g] + atomicAdd(&gfill[g], 1);
        gnodes[pos] = n;
    }
}

// ---------------- BN1 stats: run-amortized A, contiguous chunks (R7-proven) ----------------
__global__ __launch_bounds__(256) void k_stats(const float* __restrict__ Apk, const uint2* __restrict__ Cpk,
                                               const int* __restrict__ snode, const int* __restrict__ sidx1,
                                               float* __restrict__ gsum, float* __restrict__ gsq,
                                               int E, int per_slot) {
    __shared__ float4 lsm4[256], lsq4[256];
    const int t = threadIdx.x;
    const int s = t >> 6, l = t & 63;
    const float4* A4 = (const float4*)Apk;
    const long base = (long)(blockIdx.x * 4 + s) * per_slot;
    const int e0 = (int)min((long)E, base);
    const int e1 = (int)min((long)E, base + per_slot);
    float4 sm = {0.f, 0.f, 0.f, 0.f}, s2 = {0.f, 0.f, 0.f, 0.f};
    float4 csr = {0.f, 0.f, 0.f, 0.f};
    float4 a = {0.f, 0.f, 0.f, 0.f};
    int cur_n = -1, runk = 0;
    for (int e = e0; e < e1; e++) {
        int n = snode[e];
        int m = sidx1[e];
        if (n != cur_n) {
            if (runk) {
                float fk = (float)runk;
                sm.x += fmaf(fk, a.x, csr.x);
                sm.y += fmaf(fk, a.y, csr.y);
                sm.z += fmaf(fk, a.z, csr.z);
                sm.w += fmaf(fk, a.w, csr.w);
                float t0 = fmaf(fk, a.x, 2.f * csr.x); s2.x = fmaf(a.x, t0, s2.x);
                float t1 = fmaf(fk, a.y, 2.f * csr.y); s2.y = fmaf(a.y, t1, s2.y);
                float t2 = fmaf(fk, a.z, 2.f * csr.z); s2.z = fmaf(a.z, t2, s2.z);
                float t3 = fmaf(fk, a.w, 2.f * csr.w); s2.w = fmaf(a.w, t3, s2.w);
            }
            a = A4[(size_t)n * 64 + l];
            cur_n = n; runk = 0;
            csr.x = 0.f; csr.y = 0.f; csr.z = 0.f; csr.w = 0.f;
        }
        uint2 p = Cpk[(size_t)m * 64 + l];
        float c0 = bflo(p.x), c1 = bfhi(p.x), c2 = bflo(p.y), c3 = bfhi(p.y);
        csr.x += c0; csr.y += c1; csr.z += c2; csr.w += c3;
        s2.x = fmaf(c0, c0, s2.x);
        s2.y = fmaf(c1, c1, s2.y);
        s2.z = fmaf(c2, c2, s2.z);
        s2.w = fmaf(c3, c3, s2.w);
        runk++;
    }
    if (runk) {
        float fk = (float)runk;
        sm.x += fmaf(fk, a.x, csr.x);
        sm.y += fmaf(fk, a.y, csr.y);
        sm.z += fmaf(fk, a.z, csr.z);
        sm.w += fmaf(fk, a.w, csr.w);
        float t0 = fmaf(fk, a.x, 2.f * csr.x); s2.x = fmaf(a.x, t0, s2.x);
        float t1 = fmaf(fk, a.y, 2.f * csr.y); s2.y = fmaf(a.y, t1, s2.y);
        float t2 = fmaf(fk, a.z, 2.f * csr.z); s2.z = fmaf(a.z, t2, s2.z);
        float t3 = fmaf(fk, a.w, 2.f * csr.w); s2.w = fmaf(a.w, t3, s2.w);
    }
    lsm4[t] = sm;
    lsq4[t] = s2;
    __syncthreads();
    const float* fm = (const float*)lsm4;
    const float* fq = (const float*)lsq4;
    float vs = fm[t] + fm[256 + t] + fm[512 + t] + fm[768 + t];
    float vq = fq[t] + fq[256 + t] + fq[512 + t] + fq[768 + t];
    atomicAdd(&gsum[t], vs);
    atomicAdd(&gsq[t], vq);
}

// packed j -> original channel; writes packed scale/shift
__global__ __launch_bounds__(256) void k_bn1fin(const float* __restrict__ sum, const float* __restrict__ sq,
                                                const float* __restrict__ g, const float* __restrict__ b,
                                                float* __restrict__ scale, float* __restrict__ shift, float invE) {
    int j = threadIdx.x;
    int l = j >> 2, k = j & 3;
    int ch = (k < 2) ? (2 * l + k) : (128 + 2 * l + (k - 2));
    float mu = sum[j] * invE;
    float var = sq[j] * invE - mu * mu;
    float sc = g[ch] * rsqrtf(var + EPS_BN);
    scale[j] = sc;
    shift[j] = fmaf(-mu, sc, b[ch]);
}

// ---------------- fused msg + segment softmax aggregation (2 waves/block, 1 node/wave) ----------------
__global__ __launch_bounds__(128) void k_aggr(const float* __restrict__ Apk, const uint2* __restrict__ Cpk,
                                              const int* __restrict__ rowptr, const int* __restrict__ sidx1,
                                              const float* __restrict__ scale_pk, const float* __restrict__ shift_pk,
                                              const float* __restrict__ tptr, float* __restrict__ out, int N) {
    const int n = blockIdx.x * 2 + (threadIdx.x >> 6);
    if (n >= N) return;
    const int l = threadIdx.x & 63;
    const float t2 = tptr[0] * LOG2E;
    const float4 sc = ((const float4*)scale_pk)[l];
    const float4 sh = ((const float4*)shift_pk)[l];
    const float4 ap = ((const float4*)Apk)[(size_t)n * 64 + l];
    const float sfx = -sc.x * LOG2E, sfy = -sc.y * LOG2E;
    const float bfx = -fmaf(ap.x, sc.x, sh.x) * LOG2E;
    const float bfy = -fmaf(ap.y, sc.y, sh.y) * LOG2E;
    const float scz = sc.z * LOG2E, scw = sc.w * LOG2E;
    const float bcz = fmaf(ap.z, sc.z, sh.z) * LOG2E;
    const float bcw = fmaf(ap.w, sc.w, sh.w) * LOG2E;
    const int e0 = rowptr[n], e1 = rowptr[n + 1];
    float den0 = 0.f, num0 = 0.f, den1 = 0.f, num1 = 0.f;
    uint2 pnext = {0u, 0u};
    if (e0 < e1) pnext = Cpk[(size_t)sidx1[e0] * 64 + l];
    for (int e = e0; e < e1; e++) {
        uint2 p = pnext;
        if (e + 1 < e1) pnext = Cpk[(size_t)sidx1[e + 1] * 64 + l];
        float ef0 = fexp2(fmaf(bflo(p.x), sfx, bfx));
        float ef1 = fexp2(fmaf(bfhi(p.x), sfy, bfy));
        float u0  = fexp2(fmaf(bflo(p.y), scz, bcz));
        float u1  = fexp2(fmaf(bfhi(p.y), scw, bcw));
        float sig0 = __builtin_amdgcn_rcpf(1.f + ef0);
        float sig1 = __builtin_amdgcn_rcpf(1.f + ef1);
        float sp0 = LN2 * flog2(1.f + u0);
        float sp1 = LN2 * flog2(1.f + u1);
        float msg0 = sig0 * sp0;
        float msg1 = sig1 * sp1;
        float w0 = fexp2(t2 * msg0);
        float w1 = fexp2(t2 * msg1);
        den0 += w0; num0 = fmaf(msg0, w0, num0);
        den1 += w1; num1 = fmaf(msg1, w1, num1);
    }
    float2 o;
    o.x = (e1 > e0) ? num0 / den0 : 0.f;
    o.y = (e1 > e0) ? num1 / den1 : 0.f;
    ((float2*)out)[(size_t)n * 64 + l] = o;
}

// ---------------- BN2 ----------------
__global__ __launch_bounds__(128) void k_bn2stats(const float* __restrict__ out, float* __restrict__ sum,
                                                  float* __restrict__ sq, int N) {
    const int c = threadIdx.x;
    const int n0 = blockIdx.x * 64;
    const int nend = min(n0 + 64, N);
    float sm = 0.f, s2 = 0.f;
    for (int n = n0; n < nend; n++) {
        float v = out[(size_t)n * 128 + c];
        sm += v;
        s2 = fmaf(v, v, s2);
    }
    atomicAdd(&sum[c], sm);
    atomicAdd(&sq[c], s2);
}

__global__ __launch_bounds__(128) void k_bn2fin(const float* __restrict__ sum, const float* __restrict__ sq,
                                                const float* __restrict__ g, const float* __restrict__ b,
                                                float* __restrict__ scale, float* __restrict__ shift, float invN) {
    int j = threadIdx.x;
    float mu = sum[j] * invN;
    float var = sq[j] * invN - mu * mu;
    float sc = g[j] * rsqrtf(var + EPS_BN);
    scale[j] = sc;
    shift[j] = fmaf(-mu, sc, b[j]);
}

// ---------------- residual+softplus + mean-pool ----------------
template<int SPLIT>
__global__ __launch_bounds__(128) void k_h2pool(const float* __restrict__ out, const float* __restrict__ h,
                                                const int* __restrict__ gptr, const int* __restrict__ gnodes,
                                                const float* __restrict__ scale, const float* __restrict__ shift,
                                                float* __restrict__ pooled) {
    const int g = blockIdx.x & 127;
    const int sp = blockIdx.x >> 7;
    const int c = threadIdx.x;
    const float sc = scale[c], sh = shift[c];
    const int i0 = gptr[g], i1 = gptr[g + 1];
    float acc = 0.f;
    for (int i = i0 + sp; i < i1; i += SPLIT) {
        int n = gnodes[i];
        float v = fmaf(out[(size_t)n * 128 + c], sc, sh) + h[(size_t)n * 128 + c];
        acc += softplus_fast(v);
    }
    if (acc != 0.f) atomicAdd(&pooled[g * 128 + c], acc);
}

// ---------------- head ----------------
__global__ __launch_bounds__(256) void k_head(const float* __restrict__ pooled, const int* __restrict__ gcount,
                                              const float* __restrict__ l1w, const float* __restrict__ l1b,
                                              const float* __restrict__ outw, const float* __restrict__ outb,
                                              float* __restrict__ dout) {
    __shared__ float p[128];
    __shared__ float red[256];
    const int g = blockIdx.x;
    const int j = threadIdx.x;
    if (j < 128) {
        float cnt = (float)max(gcount[g], 1);
        p[j] = pooled[g * 128 + j] / cnt;
    }
    __syncthreads();
    float acc = l1b[j];
    for (int k = 0; k < 128; k++) acc = fmaf(p[k], l1w[k * 256 + j], acc);
    red[j] = softplus_fast(acc) * outw[j];
    __syncthreads();
    for (int s = 128; s > 0; s >>= 1) {
        if (j < s) red[j] += red[j + s];
        __syncthreads();
    }
    if (j == 0) dout[g] = red[0] + outb[0];
}

// ---------------- launch ----------------
extern "C" void kernel_launch(void* const* d_in, const int* in_sizes, int n_in,
                              void* d_out, int out_size, void* d_ws, size_t ws_size,
                              hipStream_t stream) {
    const float* x        = (const float*)d_in[0];
    const float* hedge    = (const float*)d_in[1];
    const int*   iri      = (const int*)d_in[2];
    const int*   batch    = (const int*)d_in[3];
    const float* embed_w  = (const float*)d_in[5];
    const float* embed_b  = (const float*)d_in[6];
    const float* bembed_w = (const float*)d_in[7];
    const float* bembed_b = (const float*)d_in[8];
    const float* lin_w    = (const float*)d_in[9];
    const float* lin_b    = (const float*)d_in[10];
    const float* bn1_g    = (const float*)d_in[11];
    const float* bn1_b    = (const float*)d_in[12];
    const float* bn2_g    = (const float*)d_in[13];
    const float* bn2_b    = (const float*)d_in[14];
    const float* aggr_t   = (const float*)d_in[15];
    const float* l1_w     = (const float*)d_in[16];
    const float* l1_b     = (const float*)d_in[17];
    const float* out_w    = (const float*)d_in[18];
    const float* out_b    = (const float*)d_in[19];

    const int N   = in_sizes[0] / 92;
    const int NHE = in_sizes[1] / 40;
    const int E   = in_sizes[2] / 3;
    const int* idx0 = iri;
    const int* idx1 = iri + E;

    float* ws = (float*)d_ws;
    size_t off = 0;
    auto alloc = [&](size_t elems) -> float* {
        float* p = ws + off;
        off += (elems + 63) & ~(size_t)63;
        return p;
    };
    float* h      = alloc((size_t)N * 128);
    float* cf     = alloc((size_t)NHE * 128);
    float* Apk    = alloc((size_t)N * 256);        // packed f32
    float* Cpk    = alloc((size_t)NHE * 128);      // packed bf16 (NHE*256 u16)
    unsigned short* embB  = (unsigned short*)alloc(8192);    // 128x128 bf16
    unsigned short* bembB = (unsigned short*)alloc(8192);
    unsigned short* waB   = (unsigned short*)alloc(16384);   // 128x256 bf16
    unsigned short* wcB   = (unsigned short*)alloc(16384);
    int*   rowptr = (int*)alloc((size_t)N + 1);
    int*   snode  = (int*)alloc((size_t)E);
    int*   sidx1  = (int*)alloc((size_t)E);
    int*   gptr   = (int*)alloc(129);
    int*   gnodes = (int*)alloc((size_t)N);
    int*   bsum   = (int*)alloc(256);
    int*   bofs   = (int*)alloc(256);
    float* bn1_scale = alloc(256);
    float* bn1_shift = alloc(256);
    float* bn2_scale = alloc(128);
    float* bn2_shift = alloc(128);
    float* outbuf = alloc((size_t)N * 128);
    // contiguous zero region
    float* zbase  = ws + off;
    int*   hist   = (int*)alloc((size_t)N);
    int*   fill   = (int*)alloc((size_t)N);
    int*   gfill  = (int*)alloc(128);
    float* bn1_sum = alloc(256);
    float* bn1_sq  = alloc(256);
    float* bn2_sum = alloc(128);
    float* bn2_sq  = alloc(128);
    float* pooled  = alloc(128 * 128);
    int*   gcount  = (int*)alloc(128);
    size_t zbytes = (size_t)((ws + off) - zbase) * sizeof(float);
    (void)ws_size;  // ~160MB; fit verified R1-R9

    hipMemsetAsync(zbase, 0, zbytes, stream);

    // bf16 weight prep + MFMA GEMMs
    k_prepw<<<384, 256, 0, stream>>>(embed_w, bembed_w, lin_w, embB, bembB, waB, wcB);
    const int mtN   = (N + 31) / 32;
    const int mtNHE = (NHE + 31) / 32;
    mfma_gemm<92, 128, 0><<<mtN * 2, 256, 0, stream>>>(x, embB, embed_b, h, N);
    mfma_gemm<40, 128, 0><<<mtNHE * 2, 256, 0, stream>>>(hedge, bembB, bembed_b, cf, NHE);
    mfma_gemm<128, 256, 1><<<mtN * 4, 256, 0, stream>>>(h, waB, lin_b, Apk, N);
    mfma_gemm<128, 256, 2><<<mtNHE * 4, 256, 0, stream>>>(cf, wcB, nullptr, Cpk, NHE);

    // edge CSR build (counting sort by idx0)
    k_hist<<<(E + 255) / 256, 256, 0, stream>>>(idx0, hist, E);
    int nchunk = (N + 255) / 256;   // 196 <= 256
    k_scan1<<<nchunk, 256, 0, stream>>>(hist, rowptr + 1, bsum, N);
    k_scan2<<<1, 256, 0, stream>>>(bsum, bofs, nchunk);
    k_scan3<<<nchunk, 256, 0, stream>>>(rowptr, bofs, N);
    k_scatter<<<(E + 255) / 256, 256, 0, stream>>>(idx0, idx1, rowptr, fill, snode, sidx1, E);

    // graph CSR build (counting sort by batch)
    k_gcount<<<(N + 127) / 128, 128, 0, stream>>>(batch, gcount, N);
    k_gscan<<<1, 128, 0, stream>>>(gcount, gptr);
    k_gscatter<<<(N + 127) / 128, 128, 0, stream>>>(batch, gptr, gfill, gnodes, N);

    // BN1 stats (single-pass, run-amortized, R7-proven) + finalize
    const int STATS_BLOCKS = 2048;              // x4 waves = 8192 slots
    int per_slot = (E + STATS_BLOCKS * 4 - 1) / (STATS_BLOCKS * 4);
    k_stats<<<STATS_BLOCKS, 256, 0, stream>>>(Apk, (const uint2*)Cpk, snode, sidx1, bn1_sum, bn1_sq, E, per_slot);
    k_bn1fin<<<1, 256, 0, stream>>>(bn1_sum, bn1_sq, bn1_g, bn1_b, bn1_scale, bn1_shift, 1.0f / (float)E);

    // fused message + softmax aggregation (2 nodes per block)
    k_aggr<<<(N + 1) / 2, 128, 0, stream>>>(Apk, (const uint2*)Cpk, rowptr, sidx1, bn1_scale, bn1_shift, aggr_t, outbuf, N);

    // BN2 + residual/softplus + pool
    k_bn2stats<<<(N + 63) / 64, 128, 0, stream>>>(outbuf, bn2_sum, bn2_sq, N);
    k_bn2fin<<<1, 128, 0, stream>>>(bn2_sum, bn2_sq, bn2_g, bn2_b, bn2_scale, bn2_shift, 1.0f / (float)N);
    k_h2pool<16><<<128 * 16, 128, 0, stream>>>(outbuf, h, gptr, gnodes, bn2_scale, bn2_shift, pooled);

    // head
    k_head<<<128, 256, 0, stream>>>(pooled, gcount, l1_w, l1_b, out_w, out_b, (float*)d_out);
}

// Round 11
// 656.879 us; speedup vs baseline: 1.5370x; 1.0473x over previous
//
#include <hip/hip_runtime.h>
#include <hip/hip_bf16.h>

// CrystalHypergraphConv — MI355X implementation.
//
// Decomposition: z[e] = A[idx0[e]] + C[idx1[e]] where
//   A = h @ (lin_w[0:128]+lin_w[256:384]) + lin_b   [N,256]
//   C = connect_feats @ lin_w[128:256]              [NHE,256]
// C stored bf16-packed; lane l owns channels {2l,2l+1,128+2l,129+2l}.
//
// R10 -> R11:
//  * k_stats was gather-latency-bound (118us, VALUBusy 20%, fabric 23%, occ 71%,
//    1 outstanding gather/wave). Now 4-wide: int4 index loads + 4 independent
//    C gathers in flight per iteration.
//  * k_aggr: 4-deep rolling prefetch (double-buffered 4-batches).
//  * mfma_gemm: removed column-group duplication (CT col-tiles per wave,
//    one A staging per 32-row tile instead of NCOL/64).
//  * CSR build trims: hist+gcount merged; snode filled without atomics;
//    scatter writes sidx1 only.

#define EPS_BN 1e-5f
#define LOG2E 1.4426950408889634f
#define LN2   0.6931471805599453f

typedef __attribute__((ext_vector_type(8))) short bf16x8;
typedef __attribute__((ext_vector_type(4))) float f32x4;

__device__ __forceinline__ float fexp2(float x) {
#if __has_builtin(__builtin_amdgcn_exp2f)
    return __builtin_amdgcn_exp2f(x);
#else
    return __expf(x * LN2);
#endif
}
__device__ __forceinline__ float flog2(float x) {
#if __has_builtin(__builtin_amdgcn_logf)
    return __builtin_amdgcn_logf(x);
#else
    return __logf(x) * LOG2E;
#endif
}
__device__ __forceinline__ float softplus_fast(float x) {
    return LN2 * flog2(1.f + fexp2(x * LOG2E));
}

__device__ __forceinline__ unsigned short f2bf(float f) {
    unsigned u = __float_as_uint(f);
    unsigned r = (u + 0x7fffu + ((u >> 16) & 1u)) >> 16;   // RNE
    return (unsigned short)r;
}
__device__ __forceinline__ float bflo(unsigned u) { return __uint_as_float(u << 16); }
__device__ __forceinline__ float bfhi(unsigned u) { return __uint_as_float(u & 0xffff0000u); }

// packed channel permutation for NCOL=256
__device__ __forceinline__ int perm256(int j) {
    return (j < 128) ? ((j >> 1) * 4 + (j & 1)) : (((j - 128) >> 1) * 4 + 2 + (j & 1));
}

// ---------------- weight prep: bf16 copies (zero-padded K to 128) ----------------
__global__ __launch_bounds__(256) void k_prepw(const float* __restrict__ ew, const float* __restrict__ bw,
                                               const float* __restrict__ lw,
                                               unsigned short* __restrict__ embB, unsigned short* __restrict__ bembB,
                                               unsigned short* __restrict__ waB, unsigned short* __restrict__ wcB) {
    int i = blockIdx.x * 256 + threadIdx.x;          // 0..98303
    if (i < 16384) {                                 // embB [128x128], K=92 padded
        int k = i >> 7, nn = i & 127;
        embB[i] = f2bf(k < 92 ? ew[k * 128 + nn] : 0.f);
    } else if (i < 32768) {                          // bembB [128x128], K=40 padded
        int j = i - 16384;
        int k = j >> 7, nn = j & 127;
        bembB[j] = f2bf(k < 40 ? bw[k * 128 + nn] : 0.f);
    } else if (i < 65536) {                          // waB [128x256] = lw[0:128]+lw[256:384]
        int j = i - 32768;
        waB[j] = f2bf(lw[j] + lw[j + 65536]);
    } else {                                         // wcB [128x256] = lw[128:256]
        int j = i - 65536;
        wcB[j] = f2bf(lw[j + 32768]);
    }
}

// ---------------- MFMA GEMM: out[M,NCOL] = bf16(in[M,KIN]) @ Wb[128,NCOL] + bias ----------------
// block = 256 thr = 4 waves; 32 rows/block; wave w covers CT=NCOL/64 col-tiles.
// OMODE: 0 natural f32; 1 packed f32 (NCOL=256); 2 packed bf16 (NCOL=256)
template<int KIN, int NCOL, int OMODE>
__global__ __launch_bounds__(256) void mfma_gemm(
    const float* __restrict__ in, const unsigned short* __restrict__ Wb,
    const float* __restrict__ bias, void* __restrict__ outv, int M)
{
    constexpr int CT = NCOL / 64;                    // col-tiles per wave
    const int r0 = blockIdx.x * 32;
    const int t = threadIdx.x;
    const int w = t >> 6;
    const int l = t & 63;
    const int m = l & 15, q = l >> 4;

    __shared__ __align__(16) unsigned short als[4096];   // [half][kc*4+quad][m][j]

    // stage A: 32 rows x 128 k, f32 -> bf16, frag-major layout
    for (int it = 0; it < 16; it++) {
        int i = it * 256 + t;                        // 0..4095
        int r = i >> 7, k = i & 127;
        int gr = r0 + r;
        float v = (gr < M && k < KIN) ? in[(size_t)gr * KIN + k] : 0.f;
        int idx = (r >> 4) * 2048 + (((k >> 5) * 4 + ((k >> 3) & 3)) * 16 + (r & 15)) * 8 + (k & 7);
        als[idx] = f2bf(v);
    }

    // B frags: 4 k-chunks x CT col-tiles x 8 bf16 per lane
    bf16x8 bf[4][CT];
#pragma unroll
    for (int kc = 0; kc < 4; kc++) {
#pragma unroll
        for (int c = 0; c < CT; c++) {
            int n = (w * CT + c) * 16 + m;
#pragma unroll
            for (int j = 0; j < 8; j++) {
                int k = kc * 32 + q * 8 + j;
                bf[kc][c][j] = (short)Wb[(size_t)k * NCOL + n];
            }
        }
    }
    __syncthreads();

    f32x4 acc[CT][2];
#pragma unroll
    for (int c = 0; c < CT; c++) { acc[c][0] = (f32x4){0.f,0.f,0.f,0.f}; acc[c][1] = (f32x4){0.f,0.f,0.f,0.f}; }
    const bf16x8* af = (const bf16x8*)als;           // frag index: half*256 + kc*64 + l
#pragma unroll
    for (int kc = 0; kc < 4; kc++) {
        bf16x8 a0 = af[kc * 64 + l];                 // rows r0..r0+15
        bf16x8 a1 = af[256 + kc * 64 + l];           // rows r0+16..r0+31
#pragma unroll
        for (int c = 0; c < CT; c++) {
            acc[c][0] = __builtin_amdgcn_mfma_f32_16x16x32_bf16(a0, bf[kc][c], acc[c][0], 0, 0, 0);
            acc[c][1] = __builtin_amdgcn_mfma_f32_16x16x32_bf16(a1, bf[kc][c], acc[c][1], 0, 0, 0);
        }
    }

#pragma unroll
    for (int c = 0; c < CT; c++) {
        int n = (w * CT + c) * 16 + m;
        float bv = bias ? bias[n] : 0.f;
        const int pj = (OMODE != 0) ? perm256(n) : n;
#pragma unroll
        for (int h = 0; h < 2; h++) {
#pragma unroll
            for (int r = 0; r < 4; r++) {
                int row = r0 + h * 16 + q * 4 + r;
                if (row < M) {
                    float val = acc[c][h][r] + bv;
                    if (OMODE == 0)      ((float*)outv)[(size_t)row * NCOL + n] = val;
                    else if (OMODE == 1) ((float*)outv)[(size_t)row * 256 + pj] = val;
                    else                 ((unsigned short*)outv)[(size_t)row * 256 + pj] = f2bf(val);
                }
            }
        }
    }
}

// ---------------- histograms: idx0 -> hist, batch -> gcount (merged) ----------------
__global__ __launch_bounds__(256) void k_hist2(const int* __restrict__ idx0, const int* __restrict__ batch,
                                               int* __restrict__ hist, int* __restrict__ gcount, int E, int N) {
    int i = blockIdx.x * 256 + threadIdx.x;
    if (i < E) atomicAdd(&hist[idx0[i]], 1);
    if (i < N) atomicAdd(&gcount[batch[i]], 1);
}

__global__ __launch_bounds__(256) void k_scan1(const int* __restrict__ hist, int* __restrict__ incl,
                                               int* __restrict__ bsum, int N) {
    __shared__ int s[256];
    int i = blockIdx.x * 256 + threadIdx.x;
    int v = (i < N) ? hist[i] : 0;
    s[threadIdx.x] = v;
    __syncthreads();
    for (int ofs = 1; ofs < 256; ofs <<= 1) {
        int t = (threadIdx.x >= ofs) ? s[threadIdx.x - ofs] : 0;
        __syncthreads();
        s[threadIdx.x] += t;
        __syncthreads();
    }
    if (i < N) incl[i] = s[threadIdx.x];
    if (threadIdx.x == 255) bsum[blockIdx.x] = s[255];
}

__global__ __launch_bounds__(256) void k_scan2(const int* __restrict__ bsum, int* __restrict__ bofs, int nb) {
    __shared__ int s[256];
    int v = (threadIdx.x < nb) ? bsum[threadIdx.x] : 0;
    s[threadIdx.x] = v;
    __syncthreads();
    for (int ofs = 1; ofs < 256; ofs <<= 1) {
        int t = (threadIdx.x >= ofs) ? s[threadIdx.x - ofs] : 0;
        __syncthreads();
        s[threadIdx.x] += t;
        __syncthreads();
    }
    if (threadIdx.x < nb) bofs[threadIdx.x] = s[threadIdx.x] - v;
}

__global__ __launch_bounds__(256) void k_scan3(int* __restrict__ rowptr, const int* __restrict__ bofs, int N) {
    int i = blockIdx.x * 256 + threadIdx.x;
    if (i < N) rowptr[i + 1] += bofs[blockIdx.x];
    if (i == 0 && blockIdx.x == 0) rowptr[0] = 0;
}

// scatter sidx1 only (snode filled separately without atomics)
__global__ __launch_bounds__(256) void k_scatter(const int* __restrict__ idx0, const int* __restrict__ idx1,
                                                 const int* __restrict__ rowptr, int* __restrict__ fill,
                                                 int* __restrict__ sidx1, int E) {
    int e = blockIdx.x * 256 + threadIdx.x;
    if (e < E) {
        int n = idx0[e];
        int pos = rowptr[n] + atomicAdd(&fill[n], 1);
        sidx1[pos] = idx1[e];
    }
}

__global__ __launch_bounds__(256) void k_fillsnode(const int* __restrict__ rowptr, int* __restrict__ snode, int N) {
    int n = blockIdx.x * 256 + threadIdx.x;
    if (n < N) {
        int a = rowptr[n], b = rowptr[n + 1];
        for (int e = a; e < b; e++) snode[e] = n;
    }
}

// ---------------- graph CSR build ----------------
__global__ __launch_bounds__(128) void k_gscan(const int* __restrict__ gcount, int* __restrict__ gptr) {
    __shared__ int s[128];
    int t = threadIdx.x;
    s[t] = gcount[t];
    __syncthreads();
    for (int ofs = 1; ofs < 128; ofs <<= 1) {
        int v = (t >= ofs) ? s[t - ofs] : 0;
        __syncthreads();
        s[t] += v;
        __syncthreads();
    }
    gptr[t + 1] = s[t];
    if (t == 0) gptr[0] = 0;
}

__global__ __launch_bounds__(128) void k_gscatter(const int* __restrict__ batch, const int* __restrict__ gptr,
                                                  int* __restrict__ gfill, int* __restrict__ gnodes, int N) {
    int n = blockIdx.x * 128 + threadIdx.x;
    if (n < N) {
        int g = batch[n];
        int pos = gptr[g] + atomicAdd(&gfill[g], 1);
        gnodes[pos] = n;
    }
}

// ---------------- BN1 stats: run-amortized A, 4-wide batched gathers ----------------
__global__ __launch_bounds__(256) void k_stats(const float* __restrict__ Apk, const uint2* __restrict__ Cpk,
                                               const int* __restrict__ snode, const int* __restrict__ sidx1,
                                               float* __restrict__ gsum, float* __restrict__ gsq,
                                               int E, int per_slot) {
    __shared__ float4 lsm4[256], lsq4[256];
    const int t = threadIdx.x;
    const int s = t >> 6, l = t & 63;
    const float4* A4 = (const float4*)Apk;
    const long base = (long)(blockIdx.x * 4 + s) * per_slot;
    const int e0 = (int)min((long)E, base);
    const int e1 = (int)min((long)E, base + per_slot);
    float4 sm = {0.f, 0.f, 0.f, 0.f}, s2 = {0.f, 0.f, 0.f, 0.f};
    float4 csr = {0.f, 0.f, 0.f, 0.f};
    float4 a = {0.f, 0.f, 0.f, 0.f};
    int cur_n = -1, runk = 0;

    auto flush = [&]() {
        if (runk) {
            float fk = (float)runk;
            sm.x += fmaf(fk, a.x, csr.x);
            sm.y += fmaf(fk, a.y, csr.y);
            sm.z += fmaf(fk, a.z, csr.z);
            sm.w += fmaf(fk, a.w, csr.w);
            float t0 = fmaf(fk, a.x, 2.f * csr.x); s2.x = fmaf(a.x, t0, s2.x);
            float t1 = fmaf(fk, a.y, 2.f * csr.y); s2.y = fmaf(a.y, t1, s2.y);
            float t2 = fmaf(fk, a.z, 2.f * csr.z); s2.z = fmaf(a.z, t2, s2.z);
            float t3 = fmaf(fk, a.w, 2.f * csr.w); s2.w = fmaf(a.w, t3, s2.w);
        }
    };
    auto proc = [&](int n, uint2 p) {
        if (n != cur_n) {                           // wave-uniform
            flush();
            a = A4[(size_t)n * 64 + l];
            cur_n = n; runk = 0;
            csr.x = 0.f; csr.y = 0.f; csr.z = 0.f; csr.w = 0.f;
        }
        float c0 = bflo(p.x), c1 = bfhi(p.x), c2 = bflo(p.y), c3 = bfhi(p.y);
        csr.x += c0; csr.y += c1; csr.z += c2; csr.w += c3;
        s2.x = fmaf(c0, c0, s2.x);
        s2.y = fmaf(c1, c1, s2.y);
        s2.z = fmaf(c2, c2, s2.z);
        s2.w = fmaf(c3, c3, s2.w);
        runk++;
    };

    int e = e0;
    for (; e + 4 <= e1; e += 4) {                   // e0 4-aligned (per_slot % 4 == 0)
        int4 nn = *(const int4*)(snode + e);        // wave-broadcast 16B
        int4 mm = *(const int4*)(sidx1 + e);
        uint2 p0 = Cpk[(size_t)mm.x * 64 + l];      // 4 independent gathers in flight
        uint2 p1 = Cpk[(size_t)mm.y * 64 + l];
        uint2 p2 = Cpk[(size_t)mm.z * 64 + l];
        uint2 p3 = Cpk[(size_t)mm.w * 64 + l];
        proc(nn.x, p0); proc(nn.y, p1); proc(nn.z, p2); proc(nn.w, p3);
    }
    for (; e < e1; e++) proc(snode[e], Cpk[(size_t)sidx1[e] * 64 + l]);
    flush();

    lsm4[t] = sm;
    lsq4[t] = s2;
    __syncthreads();
    const float* fm = (const float*)lsm4;
    const float* fq = (const float*)lsq4;
    float vs = fm[t] + fm[256 + t] + fm[512 + t] + fm[768 + t];
    float vq = fq[t] + fq[256 + t] + fq[512 + t] + fq[768 + t];
    atomicAdd(&gsum[t], vs);
    atomicAdd(&gsq[t], vq);
}

// packed j -> original channel; writes packed scale/shift
__global__ __launch_bounds__(256) void k_bn1fin(const float* __restrict__ sum, const float* __restrict__ sq,
                                                const float* __restrict__ g, const float* __restrict__ b,
                                                float* __restrict__ scale, float* __restrict__ shift, float invE) {
    int j = threadIdx.x;
    int l = j >> 2, k = j & 3;
    int ch = (k < 2) ? (2 * l + k) : (128 + 2 * l + (k - 2));
    float mu = sum[j] * invE;
    float var = sq[j] * invE - mu * mu;
    float sc = g[ch] * rsqrtf(var + EPS_BN);
    scale[j] = sc;
    shift[j] = fmaf(-mu, sc, b[ch]);
}

// ---------------- fused msg + segment softmax aggregation (2 waves/block, 1 node/wave) ----------------
// 4-deep rolling C prefetch; exp2/log2 transcendentals with folded log2e.
__global__ __launch_bounds__(128) void k_aggr(const float* __restrict__ Apk, const uint2* __restrict__ Cpk,
                                              const int* __restrict__ rowptr, const int* __restrict__ sidx1,
                                              const float* __restrict__ scale_pk, const float* __restrict__ shift_pk,
                                              const float* __restrict__ tptr, float* __restrict__ out, int N) {
    const int n = blockIdx.x * 2 + (threadIdx.x >> 6);
    if (n >= N) return;
    const int l = threadIdx.x & 63;
    const float t2 = tptr[0] * LOG2E;
    const float4 sc = ((const float4*)scale_pk)[l];
    const float4 sh = ((const float4*)shift_pk)[l];
    const float4 ap = ((const float4*)Apk)[(size_t)n * 64 + l];
    const float sfx = -sc.x * LOG2E, sfy = -sc.y * LOG2E;
    const float bfx = -fmaf(ap.x, sc.x, sh.x) * LOG2E;
    const float bfy = -fmaf(ap.y, sc.y, sh.y) * LOG2E;
    const float scz = sc.z * LOG2E, scw = sc.w * LOG2E;
    const float bcz = fmaf(ap.z, sc.z, sh.z) * LOG2E;
    const float bcw = fmaf(ap.w, sc.w, sh.w) * LOG2E;
    const int e0 = rowptr[n], e1 = rowptr[n + 1];
    float den0 = 0.f, num0 = 0.f, den1 = 0.f, num1 = 0.f;

    auto proc = [&](uint2 p) {
        float ef0 = fexp2(fmaf(bflo(p.x), sfx, bfx));
        float ef1 = fexp2(fmaf(bfhi(p.x), sfy, bfy));
        float u0  = fexp2(fmaf(bflo(p.y), scz, bcz));
        float u1  = fexp2(fmaf(bfhi(p.y), scw, bcw));
        float sig0 = __builtin_amdgcn_rcpf(1.f + ef0);
        float sig1 = __builtin_amdgcn_rcpf(1.f + ef1);
        float sp0 = LN2 * flog2(1.f + u0);
        float sp1 = LN2 * flog2(1.f + u1);
        float msg0 = sig0 * sp0;
        float msg1 = sig1 * sp1;
        float w0 = fexp2(t2 * msg0);
        float w1 = fexp2(t2 * msg1);
        den0 += w0; num0 = fmaf(msg0, w0, num0);
        den1 += w1; num1 = fmaf(msg1, w1, num1);
    };

    if (e1 > e0) {
        uint2 cur[4];
        int cb = min(e1 - e0, 4);
#pragma unroll
        for (int i = 0; i < 4; i++)
            if (i < cb) cur[i] = Cpk[(size_t)sidx1[e0 + i] * 64 + l];
        for (int eb = e0; eb < e1; eb += 4) {
            int nb = min(max(e1 - (eb + 4), 0), 4);
            uint2 nxt[4];
#pragma unroll
            for (int i = 0; i < 4; i++)
                if (i < nb) nxt[i] = Cpk[(size_t)sidx1[eb + 4 + i] * 64 + l];
            int pb = min(e1 - eb, 4);
#pragma unroll
            for (int i = 0; i < 4; i++)
                if (i < pb) proc(cur[i]);
#pragma unroll
            for (int i = 0; i < 4; i++) cur[i] = nxt[i];
        }
    }
    float2 o;
    o.x = (e1 > e0) ? num0 / den0 : 0.f;
    o.y = (e1 > e0) ? num1 / den1 : 0.f;
    ((float2*)out)[(size_t)n * 64 + l] = o;
}

// ---------------- BN2 ----------------
__global__ __launch_bounds__(128) void k_bn2stats(const float* __restrict__ out, float* __restrict__ sum,
                                                  float* __restrict__ sq, int N) {
    const int c = threadIdx.x;
    const int n0 = blockIdx.x * 64;
    const int nend = min(n0 + 64, N);
    float sm = 0.f, s2 = 0.f;
    for (int n = n0; n < nend; n++) {
        float v = out[(size_t)n * 128 + c];
        sm += v;
        s2 = fmaf(v, v, s2);
    }
    atomicAdd(&sum[c], sm);
    atomicAdd(&sq[c], s2);
}

__global__ __launch_bounds__(128) void k_bn2fin(const float* __restrict__ sum, const float* __restrict__ sq,
                                                const float* __restrict__ g, const float* __restrict__ b,
                                                float* __restrict__ scale, float* __restrict__ shift, float invN) {
    int j = threadIdx.x;
    float mu = sum[j] * invN;
    float var = sq[j] * invN - mu * mu;
    float sc = g[j] * rsqrtf(var + EPS_BN);
    scale[j] = sc;
    shift[j] = fmaf(-mu, sc, b[j]);
}

// ---------------- residual+softplus + mean-pool ----------------
template<int SPLIT>
__global__ __launch_bounds__(128) void k_h2pool(const float* __restrict__ out, const float* __restrict__ h,
                                                const int* __restrict__ gptr, const int* __restrict__ gnodes,
                                                const float* __restrict__ scale, const float* __restrict__ shift,
                                                float* __restrict__ pooled) {
    const int g = blockIdx.x & 127;
    const int sp = blockIdx.x >> 7;
    const int c = threadIdx.x;
    const float sc = scale[c], sh = shift[c];
    const int i0 = gptr[g], i1 = gptr[g + 1];
    float acc = 0.f;
    for (int i = i0 + sp; i < i1; i += SPLIT) {
        int n = gnodes[i];
        float v = fmaf(out[(size_t)n * 128 + c], sc, sh) + h[(size_t)n * 128 + c];
        acc += softplus_fast(v);
    }
    if (acc != 0.f) atomicAdd(&pooled[g * 128 + c], acc);
}

// ---------------- head ----------------
__global__ __launch_bounds__(256) void k_head(const float* __restrict__ pooled, const int* __restrict__ gcount,
                                              const float* __restrict__ l1w, const float* __restrict__ l1b,
                                              const float* __restrict__ outw, const float* __restrict__ outb,
                                              float* __restrict__ dout) {
    __shared__ float p[128];
    __shared__ float red[256];
    const int g = blockIdx.x;
    const int j = threadIdx.x;
    if (j < 128) {
        float cnt = (float)max(gcount[g], 1);
        p[j] = pooled[g * 128 + j] / cnt;
    }
    __syncthreads();
    float acc = l1b[j];
    for (int k = 0; k < 128; k++) acc = fmaf(p[k], l1w[k * 256 + j], acc);
    red[j] = softplus_fast(acc) * outw[j];
    __syncthreads();
    for (int s = 128; s > 0; s >>= 1) {
        if (j < s) red[j] += red[j + s];
        __syncthreads();
    }
    if (j == 0) dout[g] = red[0] + outb[0];
}

// ---------------- launch ----------------
extern "C" void kernel_launch(void* const* d_in, const int* in_sizes, int n_in,
                              void* d_out, int out_size, void* d_ws, size_t ws_size,
                              hipStream_t stream) {
    const float* x        = (const float*)d_in[0];
    const float* hedge    = (const float*)d_in[1];
    const int*   iri      = (const int*)d_in[2];
    const int*   batch    = (const int*)d_in[3];
    const float* embed_w  = (const float*)d_in[5];
    const float* embed_b  = (const float*)d_in[6];
    const float* bembed_w = (const float*)d_in[7];
    const float* bembed_b = (const float*)d_in[8];
    const float* lin_w    = (const float*)d_in[9];
    const float* lin_b    = (const float*)d_in[10];
    const float* bn1_g    = (const float*)d_in[11];
    const float* bn1_b    = (const float*)d_in[12];
    const float* bn2_g    = (const float*)d_in[13];
    const float* bn2_b    = (const float*)d_in[14];
    const float* aggr_t   = (const float*)d_in[15];
    const float* l1_w     = (const float*)d_in[16];
    const float* l1_b     = (const float*)d_in[17];
    const float* out_w    = (const float*)d_in[18];
    const float* out_b    = (const float*)d_in[19];

    const int N   = in_sizes[0] / 92;
    const int NHE = in_sizes[1] / 40;
    const int E   = in_sizes[2] / 3;
    const int* idx0 = iri;
    const int* idx1 = iri + E;

    float* ws = (float*)d_ws;
    size_t off = 0;
    auto alloc = [&](size_t elems) -> float* {
        float* p = ws + off;
        off += (elems + 63) & ~(size_t)63;
        return p;
    };
    float* h      = alloc((size_t)N * 128);
    float* cf     = alloc((size_t)NHE * 128);
    float* Apk    = alloc((size_t)N * 256);        // packed f32
    float* Cpk    = alloc((size_t)NHE * 128);      // packed bf16 (NHE*256 u16)
    unsigned short* embB  = (unsigned short*)alloc(8192);    // 128x128 bf16
    unsigned short* bembB = (unsigned short*)alloc(8192);
    unsigned short* waB   = (unsigned short*)alloc(16384);   // 128x256 bf16
    unsigned short* wcB   = (unsigned short*)alloc(16384);
    int*   rowptr = (int*)alloc((size_t)N + 1);
    int*   snode  = (int*)alloc((size_t)E + 4);
    int*   sidx1  = (int*)alloc((size_t)E + 4);
    int*   gptr   = (int*)alloc(129);
    int*   gnodes = (int*)alloc((size_t)N);
    int*   bsum   = (int*)alloc(256);
    int*   bofs   = (int*)alloc(256);
    float* bn1_scale = alloc(256);
    float* bn1_shift = alloc(256);
    float* bn2_scale = alloc(128);
    float* bn2_shift = alloc(128);
    float* outbuf = alloc((size_t)N * 128);
    // contiguous zero region
    float* zbase  = ws + off;
    int*   hist   = (int*)alloc((size_t)N);
    int*   fill   = (int*)alloc((size_t)N);
    int*   gfill  = (int*)alloc(128);
    float* bn1_sum = alloc(256);
    float* bn1_sq  = alloc(256);
    float* bn2_sum = alloc(128);
    float* bn2_sq  = alloc(128);
    float* pooled  = alloc(128 * 128);
    int*   gcount  = (int*)alloc(128);
    size_t zbytes = (size_t)((ws + off) - zbase) * sizeof(float);
    (void)ws_size;  // ~160MB; fit verified R1-R10

    hipMemsetAsync(zbase, 0, zbytes, stream);

    // bf16 weight prep + MFMA GEMMs (one block covers all columns of its 32-row tile)
    k_prepw<<<384, 256, 0, stream>>>(embed_w, bembed_w, lin_w, embB, bembB, waB, wcB);
    const int mtN   = (N + 31) / 32;
    const int mtNHE = (NHE + 31) / 32;
    mfma_gemm<92, 128, 0><<<mtN, 256, 0, stream>>>(x, embB, embed_b, h, N);
    mfma_gemm<40, 128, 0><<<mtNHE, 256, 0, stream>>>(hedge, bembB, bembed_b, cf, NHE);
    mfma_gemm<128, 256, 1><<<mtN, 256, 0, stream>>>(h, waB, lin_b, Apk, N);
    mfma_gemm<128, 256, 2><<<mtNHE, 256, 0, stream>>>(cf, wcB, nullptr, Cpk, NHE);

    // edge + graph histograms (merged)
    k_hist2<<<(E + 255) / 256, 256, 0, stream>>>(idx0, batch, hist, gcount, E, N);
    int nchunk = (N + 255) / 256;   // 196 <= 256
    k_scan1<<<nchunk, 256, 0, stream>>>(hist, rowptr + 1, bsum, N);
    k_scan2<<<1, 256, 0, stream>>>(bsum, bofs, nchunk);
    k_scan3<<<nchunk, 256, 0, stream>>>(rowptr, bofs, N);
    k_scatter<<<(E + 255) / 256, 256, 0, stream>>>(idx0, idx1, rowptr, fill, sidx1, E);
    k_fillsnode<<<(N + 255) / 256, 256, 0, stream>>>(rowptr, snode, N);

    // graph CSR
    k_gscan<<<1, 128, 0, stream>>>(gcount, gptr);
    k_gscatter<<<(N + 127) / 128, 128, 0, stream>>>(batch, gptr, gfill, gnodes, N);

    // BN1 stats (4-wide gathers) + finalize
    const int STATS_BLOCKS = 2048;              // x4 waves = 8192 slots
    int per_slot = ((E + STATS_BLOCKS * 4 - 1) / (STATS_BLOCKS * 4) + 3) & ~3;  // 4-aligned
    k_stats<<<STATS_BLOCKS, 256, 0, stream>>>(Apk, (const uint2*)Cpk, snode, sidx1, bn1_sum, bn1_sq, E, per_slot);
    k_bn1fin<<<1, 256, 0, stream>>>(bn1_sum, bn1_sq, bn1_g, bn1_b, bn1_scale, bn1_shift, 1.0f / (float)E);

    // fused message + softmax aggregation (2 nodes per block)
    k_aggr<<<(N + 1) / 2, 128, 0, stream>>>(Apk, (const uint2*)Cpk, rowptr, sidx1, bn1_scale, bn1_shift, aggr_t, outbuf, N);

    // BN2 + residual/softplus + pool
    k_bn2stats<<<(N + 63) / 64, 128, 0, stream>>>(outbuf, bn2_sum, bn2_sq, N);
    k_bn2fin<<<1, 128, 0, stream>>>(bn2_sum, bn2_sq, bn2_g, bn2_b, bn2_scale, bn2_shift, 1.0f / (float)N);
    k_h2pool<16><<<128 * 16, 128, 0, stream>>>(outbuf, h, gptr, gnodes, bn2_scale, bn2_shift, pooled);

    // head
    k_head<<<128, 256, 0, stream>>>(pooled, gcount, l1_w, l1_b, out_w, out_b, (float*)d_out);
}

// Round 12
// 619.634 us; speedup vs baseline: 1.6294x; 1.0601x over previous
//
#include <hip/hip_runtime.h>
#include <hip/hip_bf16.h>

// CrystalHypergraphConv — MI355X implementation.
//
// Decomposition: z[e] = A[idx0[e]] + C[idx1[e]] where
//   A = h @ (lin_w[0:128]+lin_w[256:384]) + lin_b   [N,256]
//   C = connect_feats @ lin_w[128:256]              [NHE,256]
// C stored fp8-e4m3-packed (R12): lane l owns channels {2l,2l+1,128+2l,129+2l}
// in one dword -> per-edge gather = ONE dword (256B/row).
//
// R11 -> R12: k_stats was HBM-refetch-bound, not MLP-bound (FETCH 208MB vs
// 84MB unique = 2.5x refetch; 4-wide MLP gave only 1.18x). C table bf16->fp8
// halves the gathered bytes (25.6->12.8MB table, better L2/L3 residency).
// Native v_cvt_pk_f32_fp8 decode (2 ops/edge). k_stats batching 4->8 wide.
// Stats computed on the same fp8 values used in aggr (self-consistent BN1).

#define EPS_BN 1e-5f
#define LOG2E 1.4426950408889634f
#define LN2   0.6931471805599453f

typedef __attribute__((ext_vector_type(8))) short bf16x8;
typedef __attribute__((ext_vector_type(4))) float f32x4;
typedef __attribute__((ext_vector_type(2))) float f32x2;

__device__ __forceinline__ float fexp2(float x) {
#if __has_builtin(__builtin_amdgcn_exp2f)
    return __builtin_amdgcn_exp2f(x);
#else
    return __expf(x * LN2);
#endif
}
__device__ __forceinline__ float flog2(float x) {
#if __has_builtin(__builtin_amdgcn_logf)
    return __builtin_amdgcn_logf(x);
#else
    return __logf(x) * LOG2E;
#endif
}
__device__ __forceinline__ float softplus_fast(float x) {
    return LN2 * flog2(1.f + fexp2(x * LOG2E));
}

__device__ __forceinline__ unsigned short f2bf(float f) {
    unsigned u = __float_as_uint(f);
    unsigned r = (u + 0x7fffu + ((u >> 16) & 1u)) >> 16;   // RNE
    return (unsigned short)r;
}

// ---- fp8 e4m3 encode/decode (OCP; HW path on gfx950) ----
#if __has_builtin(__builtin_amdgcn_cvt_pk_f32_fp8) && __has_builtin(__builtin_amdgcn_cvt_pk_fp8_f32)
#define HW_FP8 1
#else
#define HW_FP8 0
#endif

__device__ __forceinline__ unsigned char f2fp8(float f) {
#if HW_FP8
    int r = __builtin_amdgcn_cvt_pk_fp8_f32(f, f, 0, false);
    return (unsigned char)(r & 0xff);
#else
    unsigned u = __float_as_uint(f);
    unsigned s = (u >> 24) & 0x80u;
    float af = fabsf(f);
    if (!(af >= 0.015625f)) {                       // subnormal / zero / tiny
        int m = (int)rintf(af * 512.f);
        if (m > 7) m = 7;
        return (unsigned char)(s | (unsigned)m);
    }
    if (af > 448.f) return (unsigned char)(s | 0x7e);
    unsigned au = __float_as_uint(af);
    unsigned r = au + 0x7ffffu + ((au >> 20) & 1u); // RNE into 3-bit mantissa
    int e8 = (int)(r >> 23) - 120;
    unsigned m = (r >> 20) & 7u;
    if (e8 > 15 || (e8 == 15 && m == 7)) return (unsigned char)(s | 0x7e);
    return (unsigned char)(s | ((unsigned)e8 << 3) | m);
#endif
}

__device__ __forceinline__ void fp8quad(unsigned p, float& a, float& b, float& c, float& d) {
#if HW_FP8
    f32x2 lo = __builtin_amdgcn_cvt_pk_f32_fp8((int)p, false);
    f32x2 hi = __builtin_amdgcn_cvt_pk_f32_fp8((int)p, true);
    a = lo.x; b = lo.y; c = hi.x; d = hi.y;
#else
    auto dec = [](unsigned byte) -> float {
        unsigned s = (byte & 0x80u) << 24;
        unsigned em = byte & 0x7fu;
        float nrm = __uint_as_float(s | ((em << 20) + 0x3C000000u));
        float sub = __uint_as_float(s | 0x3F800000u) * (float)em * 0.001953125f;
        return (em >= 8) ? nrm : sub;
    };
    a = dec(p & 0xff); b = dec((p >> 8) & 0xff);
    c = dec((p >> 16) & 0xff); d = dec(p >> 24);
#endif
}

// packed channel permutation for NCOL=256
__device__ __forceinline__ int perm256(int j) {
    return (j < 128) ? ((j >> 1) * 4 + (j & 1)) : (((j - 128) >> 1) * 4 + 2 + (j & 1));
}

// ---------------- weight prep: bf16 copies (zero-padded K to 128) ----------------
__global__ __launch_bounds__(256) void k_prepw(const float* __restrict__ ew, const float* __restrict__ bw,
                                               const float* __restrict__ lw,
                                               unsigned short* __restrict__ embB, unsigned short* __restrict__ bembB,
                                               unsigned short* __restrict__ waB, unsigned short* __restrict__ wcB) {
    int i = blockIdx.x * 256 + threadIdx.x;          // 0..98303
    if (i < 16384) {
        int k = i >> 7, nn = i & 127;
        embB[i] = f2bf(k < 92 ? ew[k * 128 + nn] : 0.f);
    } else if (i < 32768) {
        int j = i - 16384;
        int k = j >> 7, nn = j & 127;
        bembB[j] = f2bf(k < 40 ? bw[k * 128 + nn] : 0.f);
    } else if (i < 65536) {
        int j = i - 32768;
        waB[j] = f2bf(lw[j] + lw[j + 65536]);
    } else {
        int j = i - 65536;
        wcB[j] = f2bf(lw[j + 32768]);
    }
}

// ---------------- MFMA GEMM: out[M,NCOL] = bf16(in[M,KIN]) @ Wb[128,NCOL] + bias ----------------
// block = 256 thr = 4 waves; 32 rows/block; wave w covers CT=NCOL/64 col-tiles.
// OMODE: 0 natural f32; 1 packed f32 (NCOL=256); 2 packed fp8 (NCOL=256)
template<int KIN, int NCOL, int OMODE>
__global__ __launch_bounds__(256) void mfma_gemm(
    const float* __restrict__ in, const unsigned short* __restrict__ Wb,
    const float* __restrict__ bias, void* __restrict__ outv, int M)
{
    constexpr int CT = NCOL / 64;
    const int r0 = blockIdx.x * 32;
    const int t = threadIdx.x;
    const int w = t >> 6;
    const int l = t & 63;
    const int m = l & 15, q = l >> 4;

    __shared__ __align__(16) unsigned short als[4096];

    for (int it = 0; it < 16; it++) {
        int i = it * 256 + t;
        int r = i >> 7, k = i & 127;
        int gr = r0 + r;
        float v = (gr < M && k < KIN) ? in[(size_t)gr * KIN + k] : 0.f;
        int idx = (r >> 4) * 2048 + (((k >> 5) * 4 + ((k >> 3) & 3)) * 16 + (r & 15)) * 8 + (k & 7);
        als[idx] = f2bf(v);
    }

    bf16x8 bf[4][CT];
#pragma unroll
    for (int kc = 0; kc < 4; kc++) {
#pragma unroll
        for (int c = 0; c < CT; c++) {
            int n = (w * CT + c) * 16 + m;
#pragma unroll
            for (int j = 0; j < 8; j++) {
                int k = kc * 32 + q * 8 + j;
                bf[kc][c][j] = (short)Wb[(size_t)k * NCOL + n];
            }
        }
    }
    __syncthreads();

    f32x4 acc[CT][2];
#pragma unroll
    for (int c = 0; c < CT; c++) { acc[c][0] = (f32x4){0.f,0.f,0.f,0.f}; acc[c][1] = (f32x4){0.f,0.f,0.f,0.f}; }
    const bf16x8* af = (const bf16x8*)als;
#pragma unroll
    for (int kc = 0; kc < 4; kc++) {
        bf16x8 a0 = af[kc * 64 + l];
        bf16x8 a1 = af[256 + kc * 64 + l];
#pragma unroll
        for (int c = 0; c < CT; c++) {
            acc[c][0] = __builtin_amdgcn_mfma_f32_16x16x32_bf16(a0, bf[kc][c], acc[c][0], 0, 0, 0);
            acc[c][1] = __builtin_amdgcn_mfma_f32_16x16x32_bf16(a1, bf[kc][c], acc[c][1], 0, 0, 0);
        }
    }

#pragma unroll
    for (int c = 0; c < CT; c++) {
        int n = (w * CT + c) * 16 + m;
        float bv = bias ? bias[n] : 0.f;
        const int pj = (OMODE != 0) ? perm256(n) : n;
#pragma unroll
        for (int h = 0; h < 2; h++) {
#pragma unroll
            for (int r = 0; r < 4; r++) {
                int row = r0 + h * 16 + q * 4 + r;
                if (row < M) {
                    float val = acc[c][h][r] + bv;
                    if (OMODE == 0)      ((float*)outv)[(size_t)row * NCOL + n] = val;
                    else if (OMODE == 1) ((float*)outv)[(size_t)row * 256 + pj] = val;
                    else                 ((unsigned char*)outv)[(size_t)row * 256 + pj] = f2fp8(val);
                }
            }
        }
    }
}

// ---------------- histograms: idx0 -> hist, batch -> gcount (merged) ----------------
__global__ __launch_bounds__(256) void k_hist2(const int* __restrict__ idx0, const int* __restrict__ batch,
                                               int* __restrict__ hist, int* __restrict__ gcount, int E, int N) {
    int i = blockIdx.x * 256 + threadIdx.x;
    if (i < E) atomicAdd(&hist[idx0[i]], 1);
    if (i < N) atomicAdd(&gcount[batch[i]], 1);
}

__global__ __launch_bounds__(256) void k_scan1(const int* __restrict__ hist, int* __restrict__ incl,
                                               int* __restrict__ bsum, int N) {
    __shared__ int s[256];
    int i = blockIdx.x * 256 + threadIdx.x;
    int v = (i < N) ? hist[i] : 0;
    s[threadIdx.x] = v;
    __syncthreads();
    for (int ofs = 1; ofs < 256; ofs <<= 1) {
        int t = (threadIdx.x >= ofs) ? s[threadIdx.x - ofs] : 0;
        __syncthreads();
        s[threadIdx.x] += t;
        __syncthreads();
    }
    if (i < N) incl[i] = s[threadIdx.x];
    if (threadIdx.x == 255) bsum[blockIdx.x] = s[255];
}

__global__ __launch_bounds__(256) void k_scan2(const int* __restrict__ bsum, int* __restrict__ bofs, int nb) {
    __shared__ int s[256];
    int v = (threadIdx.x < nb) ? bsum[threadIdx.x] : 0;
    s[threadIdx.x] = v;
    __syncthreads();
    for (int ofs = 1; ofs < 256; ofs <<= 1) {
        int t = (threadIdx.x >= ofs) ? s[threadIdx.x - ofs] : 0;
        __syncthreads();
        s[threadIdx.x] += t;
        __syncthreads();
    }
    if (threadIdx.x < nb) bofs[threadIdx.x] = s[threadIdx.x] - v;
}

__global__ __launch_bounds__(256) void k_scan3(int* __restrict__ rowptr, const int* __restrict__ bofs, int N) {
    int i = blockIdx.x * 256 + threadIdx.x;
    if (i < N) rowptr[i + 1] += bofs[blockIdx.x];
    if (i == 0 && blockIdx.x == 0) rowptr[0] = 0;
}

__global__ __launch_bounds__(256) void k_scatter(const int* __restrict__ idx0, const int* __restrict__ idx1,
                                                 const int* __restrict__ rowptr, int* __restrict__ fill,
                                                 int* __restrict__ sidx1, int E) {
    int e = blockIdx.x * 256 + threadIdx.x;
    if (e < E) {
        int n = idx0[e];
        int pos = rowptr[n] + atomicAdd(&fill[n], 1);
        sidx1[pos] = idx1[e];
    }
}

__global__ __launch_bounds__(256) void k_fillsnode(const int* __restrict__ rowptr, int* __restrict__ snode, int N) {
    int n = blockIdx.x * 256 + threadIdx.x;
    if (n < N) {
        int a = rowptr[n], b = rowptr[n + 1];
        for (int e = a; e < b; e++) snode[e] = n;
    }
}

// ---------------- graph CSR build ----------------
__global__ __launch_bounds__(128) void k_gscan(const int* __restrict__ gcount, int* __restrict__ gptr) {
    __shared__ int s[128];
    int t = threadIdx.x;
    s[t] = gcount[t];
    __syncthreads();
    for (int ofs = 1; ofs < 128; ofs <<= 1) {
        int v = (t >= ofs) ? s[t - ofs] : 0;
        __syncthreads();
        s[t] += v;
        __syncthreads();
    }
    gptr[t + 1] = s[t];
    if (t == 0) gptr[0] = 0;
}

__global__ __launch_bounds__(128) void k_gscatter(const int* __restrict__ batch, const int* __restrict__ gptr,
                                                  int* __restrict__ gfill, int* __restrict__ gnodes, int N) {
    int n = blockIdx.x * 128 + threadIdx.x;
    if (n < N) {
        int g = batch[n];
        int pos = gptr[g] + atomicAdd(&gfill[g], 1);
        gnodes[pos] = n;
    }
}

// ---------------- BN1 stats: run-amortized A, 8-wide batched fp8 gathers ----------------
__global__ __launch_bounds__(256) void k_stats(const float* __restrict__ Apk, const unsigned* __restrict__ Cp8,
                                               const int* __restrict__ snode, const int* __restrict__ sidx1,
                                               float* __restrict__ gsum, float* __restrict__ gsq,
                                               int E, int per_slot) {
    __shared__ float4 lsm4[256], lsq4[256];
    const int t = threadIdx.x;
    const int s = t >> 6, l = t & 63;
    const float4* A4 = (const float4*)Apk;
    const long base = (long)(blockIdx.x * 4 + s) * per_slot;
    const int e0 = (int)min((long)E, base);
    const int e1 = (int)min((long)E, base + per_slot);
    float4 sm = {0.f, 0.f, 0.f, 0.f}, s2 = {0.f, 0.f, 0.f, 0.f};
    float4 csr = {0.f, 0.f, 0.f, 0.f};
    float4 a = {0.f, 0.f, 0.f, 0.f};
    int cur_n = -1, runk = 0;

    auto flush = [&]() {
        if (runk) {
            float fk = (float)runk;
            sm.x += fmaf(fk, a.x, csr.x);
            sm.y += fmaf(fk, a.y, csr.y);
            sm.z += fmaf(fk, a.z, csr.z);
            sm.w += fmaf(fk, a.w, csr.w);
            float t0 = fmaf(fk, a.x, 2.f * csr.x); s2.x = fmaf(a.x, t0, s2.x);
            float t1 = fmaf(fk, a.y, 2.f * csr.y); s2.y = fmaf(a.y, t1, s2.y);
            float t2 = fmaf(fk, a.z, 2.f * csr.z); s2.z = fmaf(a.z, t2, s2.z);
            float t3 = fmaf(fk, a.w, 2.f * csr.w); s2.w = fmaf(a.w, t3, s2.w);
        }
    };
    auto proc = [&](int n, unsigned p) {
        if (n != cur_n) {                           // wave-uniform
            flush();
            a = A4[(size_t)n * 64 + l];
            cur_n = n; runk = 0;
            csr.x = 0.f; csr.y = 0.f; csr.z = 0.f; csr.w = 0.f;
        }
        float c0, c1, c2, c3;
        fp8quad(p, c0, c1, c2, c3);
        csr.x += c0; csr.y += c1; csr.z += c2; csr.w += c3;
        s2.x = fmaf(c0, c0, s2.x);
        s2.y = fmaf(c1, c1, s2.y);
        s2.z = fmaf(c2, c2, s2.z);
        s2.w = fmaf(c3, c3, s2.w);
        runk++;
    };

    int e = e0;
    for (; e + 8 <= e1; e += 8) {                   // e0 8-aligned (per_slot % 8 == 0)
        int4 nn0 = *(const int4*)(snode + e);
        int4 nn1 = *(const int4*)(snode + e + 4);
        int4 mm0 = *(const int4*)(sidx1 + e);
        int4 mm1 = *(const int4*)(sidx1 + e + 4);
        unsigned p0 = Cp8[(size_t)mm0.x * 64 + l];  // 8 independent gathers in flight
        unsigned p1 = Cp8[(size_t)mm0.y * 64 + l];
        unsigned p2 = Cp8[(size_t)mm0.z * 64 + l];
        unsigned p3 = Cp8[(size_t)mm0.w * 64 + l];
        unsigned p4 = Cp8[(size_t)mm1.x * 64 + l];
        unsigned p5 = Cp8[(size_t)mm1.y * 64 + l];
        unsigned p6 = Cp8[(size_t)mm1.z * 64 + l];
        unsigned p7 = Cp8[(size_t)mm1.w * 64 + l];
        proc(nn0.x, p0); proc(nn0.y, p1); proc(nn0.z, p2); proc(nn0.w, p3);
        proc(nn1.x, p4); proc(nn1.y, p5); proc(nn1.z, p6); proc(nn1.w, p7);
    }
    for (; e < e1; e++) proc(snode[e], Cp8[(size_t)sidx1[e] * 64 + l]);
    flush();

    lsm4[t] = sm;
    lsq4[t] = s2;
    __syncthreads();
    const float* fm = (const float*)lsm4;
    const float* fq = (const float*)lsq4;
    float vs = fm[t] + fm[256 + t] + fm[512 + t] + fm[768 + t];
    float vq = fq[t] + fq[256 + t] + fq[512 + t] + fq[768 + t];
    atomicAdd(&gsum[t], vs);
    atomicAdd(&gsq[t], vq);
}

// packed j -> original channel; writes packed scale/shift
__global__ __launch_bounds__(256) void k_bn1fin(const float* __restrict__ sum, const float* __restrict__ sq,
                                                const float* __restrict__ g, const float* __restrict__ b,
                                                float* __restrict__ scale, float* __restrict__ shift, float invE) {
    int j = threadIdx.x;
    int l = j >> 2, k = j & 3;
    int ch = (k < 2) ? (2 * l + k) : (128 + 2 * l + (k - 2));
    float mu = sum[j] * invE;
    float var = sq[j] * invE - mu * mu;
    float sc = g[ch] * rsqrtf(var + EPS_BN);
    scale[j] = sc;
    shift[j] = fmaf(-mu, sc, b[ch]);
}

// ---------------- fused msg + segment softmax aggregation (2 waves/block, 1 node/wave) ----------------
// 4-deep rolling fp8 C prefetch; exp2/log2 transcendentals with folded log2e.
__global__ __launch_bounds__(128) void k_aggr(const float* __restrict__ Apk, const unsigned* __restrict__ Cp8,
                                              const int* __restrict__ rowptr, const int* __restrict__ sidx1,
                                              const float* __restrict__ scale_pk, const float* __restrict__ shift_pk,
                                              const float* __restrict__ tptr, float* __restrict__ out, int N) {
    const int n = blockIdx.x * 2 + (threadIdx.x >> 6);
    if (n >= N) return;
    const int l = threadIdx.x & 63;
    const float t2 = tptr[0] * LOG2E;
    const float4 sc = ((const float4*)scale_pk)[l];
    const float4 sh = ((const float4*)shift_pk)[l];
    const float4 ap = ((const float4*)Apk)[(size_t)n * 64 + l];
    const float sfx = -sc.x * LOG2E, sfy = -sc.y * LOG2E;
    const float bfx = -fmaf(ap.x, sc.x, sh.x) * LOG2E;
    const float bfy = -fmaf(ap.y, sc.y, sh.y) * LOG2E;
    const float scz = sc.z * LOG2E, scw = sc.w * LOG2E;
    const float bcz = fmaf(ap.z, sc.z, sh.z) * LOG2E;
    const float bcw = fmaf(ap.w, sc.w, sh.w) * LOG2E;
    const int e0 = rowptr[n], e1 = rowptr[n + 1];
    float den0 = 0.f, num0 = 0.f, den1 = 0.f, num1 = 0.f;

    auto proc = [&](unsigned p) {
        float c0, c1, c2, c3;
        fp8quad(p, c0, c1, c2, c3);
        float ef0 = fexp2(fmaf(c0, sfx, bfx));
        float ef1 = fexp2(fmaf(c1, sfy, bfy));
        float u0  = fexp2(fmaf(c2, scz, bcz));
        float u1  = fexp2(fmaf(c3, scw, bcw));
        float sig0 = __builtin_amdgcn_rcpf(1.f + ef0);
        float sig1 = __builtin_amdgcn_rcpf(1.f + ef1);
        float sp0 = LN2 * flog2(1.f + u0);
        float sp1 = LN2 * flog2(1.f + u1);
        float msg0 = sig0 * sp0;
        float msg1 = sig1 * sp1;
        float w0 = fexp2(t2 * msg0);
        float w1 = fexp2(t2 * msg1);
        den0 += w0; num0 = fmaf(msg0, w0, num0);
        den1 += w1; num1 = fmaf(msg1, w1, num1);
    };

    if (e1 > e0) {
        unsigned cur[4];
        int cb = min(e1 - e0, 4);
#pragma unroll
        for (int i = 0; i < 4; i++)
            if (i < cb) cur[i] = Cp8[(size_t)sidx1[e0 + i] * 64 + l];
        for (int eb = e0; eb < e1; eb += 4) {
            int nb = min(max(e1 - (eb + 4), 0), 4);
            unsigned nxt[4];
#pragma unroll
            for (int i = 0; i < 4; i++)
                if (i < nb) nxt[i] = Cp8[(size_t)sidx1[eb + 4 + i] * 64 + l];
            int pb = min(e1 - eb, 4);
#pragma unroll
            for (int i = 0; i < 4; i++)
                if (i < pb) proc(cur[i]);
#pragma unroll
            for (int i = 0; i < 4; i++) cur[i] = nxt[i];
        }
    }
    float2 o;
    o.x = (e1 > e0) ? num0 / den0 : 0.f;
    o.y = (e1 > e0) ? num1 / den1 : 0.f;
    ((float2*)out)[(size_t)n * 64 + l] = o;
}

// ---------------- BN2 ----------------
__global__ __launch_bounds__(128) void k_bn2stats(const float* __restrict__ out, float* __restrict__ sum,
                                                  float* __restrict__ sq, int N) {
    const int c = threadIdx.x;
    const int n0 = blockIdx.x * 64;
    const int nend = min(n0 + 64, N);
    float sm = 0.f, s2 = 0.f;
    for (int n = n0; n < nend; n++) {
        float v = out[(size_t)n * 128 + c];
        sm += v;
        s2 = fmaf(v, v, s2);
    }
    atomicAdd(&sum[c], sm);
    atomicAdd(&sq[c], s2);
}

__global__ __launch_bounds__(128) void k_bn2fin(const float* __restrict__ sum, const float* __restrict__ sq,
                                                const float* __restrict__ g, const float* __restrict__ b,
                                                float* __restrict__ scale, float* __restrict__ shift, float invN) {
    int j = threadIdx.x;
    float mu = sum[j] * invN;
    float var = sq[j] * invN - mu * mu;
    float sc = g[j] * rsqrtf(var + EPS_BN);
    scale[j] = sc;
    shift[j] = fmaf(-mu, sc, b[j]);
}

// ---------------- residual+softplus + mean-pool ----------------
template<int SPLIT>
__global__ __launch_bounds__(128) void k_h2pool(const float* __restrict__ out, const float* __restrict__ h,
                                                const int* __restrict__ gptr, const int* __restrict__ gnodes,
                                                const float* __restrict__ scale, const float* __restrict__ shift,
                                                float* __restrict__ pooled) {
    const int g = blockIdx.x & 127;
    const int sp = blockIdx.x >> 7;
    const int c = threadIdx.x;
    const float sc = scale[c], sh = shift[c];
    const int i0 = gptr[g], i1 = gptr[g + 1];
    float acc = 0.f;
    for (int i = i0 + sp; i < i1; i += SPLIT) {
        int n = gnodes[i];
        float v = fmaf(out[(size_t)n * 128 + c], sc, sh) + h[(size_t)n * 128 + c];
        acc += softplus_fast(v);
    }
    if (acc != 0.f) atomicAdd(&pooled[g * 128 + c], acc);
}

// ---------------- head ----------------
__global__ __launch_bounds__(256) void k_head(const float* __restrict__ pooled, const int* __restrict__ gcount,
                                              const float* __restrict__ l1w, const float* __restrict__ l1b,
                                              const float* __restrict__ outw, const float* __restrict__ outb,
                                              float* __restrict__ dout) {
    __shared__ float p[128];
    __shared__ float red[256];
    const int g = blockIdx.x;
    const int j = threadIdx.x;
    if (j < 128) {
        float cnt = (float)max(gcount[g], 1);
        p[j] = pooled[g * 128 + j] / cnt;
    }
    __syncthreads();
    float acc = l1b[j];
    for (int k = 0; k < 128; k++) acc = fmaf(p[k], l1w[k * 256 + j], acc);
    red[j] = softplus_fast(acc) * outw[j];
    __syncthreads();
    for (int s = 128; s > 0; s >>= 1) {
        if (j < s) red[j] += red[j + s];
        __syncthreads();
    }
    if (j == 0) dout[g] = red[0] + outb[0];
}

// ---------------- launch ----------------
extern "C" void kernel_launch(void* const* d_in, const int* in_sizes, int n_in,
                              void* d_out, int out_size, void* d_ws, size_t ws_size,
                              hipStream_t stream) {
    const float* x        = (const float*)d_in[0];
    const float* hedge    = (const float*)d_in[1];
    const int*   iri      = (const int*)d_in[2];
    const int*   batch    = (const int*)d_in[3];
    const float* embed_w  = (const float*)d_in[5];
    const float* embed_b  = (const float*)d_in[6];
    const float* bembed_w = (const float*)d_in[7];
    const float* bembed_b = (const float*)d_in[8];
    const float* lin_w    = (const float*)d_in[9];
    const float* lin_b    = (const float*)d_in[10];
    const float* bn1_g    = (const float*)d_in[11];
    const float* bn1_b    = (const float*)d_in[12];
    const float* bn2_g    = (const float*)d_in[13];
    const float* bn2_b    = (const float*)d_in[14];
    const float* aggr_t   = (const float*)d_in[15];
    const float* l1_w     = (const float*)d_in[16];
    const float* l1_b     = (const float*)d_in[17];
    const float* out_w    = (const float*)d_in[18];
    const float* out_b    = (const float*)d_in[19];

    const int N   = in_sizes[0] / 92;
    const int NHE = in_sizes[1] / 40;
    const int E   = in_sizes[2] / 3;
    const int* idx0 = iri;
    const int* idx1 = iri + E;

    float* ws = (float*)d_ws;
    size_t off = 0;
    auto alloc = [&](size_t elems) -> float* {
        float* p = ws + off;
        off += (elems + 63) & ~(size_t)63;
        return p;
    };
    float* h      = alloc((size_t)N * 128);
    float* cf     = alloc((size_t)NHE * 128);
    float* Apk    = alloc((size_t)N * 256);        // packed f32
    unsigned* Cp8 = (unsigned*)alloc((size_t)NHE * 64);   // packed fp8 (NHE*256 bytes)
    unsigned short* embB  = (unsigned short*)alloc(8192);
    unsigned short* bembB = (unsigned short*)alloc(8192);
    unsigned short* waB   = (unsigned short*)alloc(16384);
    unsigned short* wcB   = (unsigned short*)alloc(16384);
    int*   rowptr = (int*)alloc((size_t)N + 1);
    int*   snode  = (int*)alloc((size_t)E + 8);
    int*   sidx1  = (int*)alloc((size_t)E + 8);
    int*   gptr   = (int*)alloc(129);
    int*   gnodes = (int*)alloc((size_t)N);
    int*   bsum   = (int*)alloc(256);
    int*   bofs   = (int*)alloc(256);
    float* bn1_scale = alloc(256);
    float* bn1_shift = alloc(256);
    float* bn2_scale = alloc(128);
    float* bn2_shift = alloc(128);
    float* outbuf = alloc((size_t)N * 128);
    // contiguous zero region
    float* zbase  = ws + off;
    int*   hist   = (int*)alloc((size_t)N);
    int*   fill   = (int*)alloc((size_t)N);
    int*   gfill  = (int*)alloc(128);
    float* bn1_sum = alloc(256);
    float* bn1_sq  = alloc(256);
    float* bn2_sum = alloc(128);
    float* bn2_sq  = alloc(128);
    float* pooled  = alloc(128 * 128);
    int*   gcount  = (int*)alloc(128);
    size_t zbytes = (size_t)((ws + off) - zbase) * sizeof(float);
    (void)ws_size;  // ~150MB; fit verified R1-R11

    hipMemsetAsync(zbase, 0, zbytes, stream);

    // bf16 weight prep + MFMA GEMMs
    k_prepw<<<384, 256, 0, stream>>>(embed_w, bembed_w, lin_w, embB, bembB, waB, wcB);
    const int mtN   = (N + 31) / 32;
    const int mtNHE = (NHE + 31) / 32;
    mfma_gemm<92, 128, 0><<<mtN, 256, 0, stream>>>(x, embB, embed_b, h, N);
    mfma_gemm<40, 128, 0><<<mtNHE, 256, 0, stream>>>(hedge, bembB, bembed_b, cf, NHE);
    mfma_gemm<128, 256, 1><<<mtN, 256, 0, stream>>>(h, waB, lin_b, Apk, N);
    mfma_gemm<128, 256, 2><<<mtNHE, 256, 0, stream>>>(cf, wcB, nullptr, Cp8, NHE);

    // edge + graph histograms (merged)
    k_hist2<<<(E + 255) / 256, 256, 0, stream>>>(idx0, batch, hist, gcount, E, N);
    int nchunk = (N + 255) / 256;
    k_scan1<<<nchunk, 256, 0, stream>>>(hist, rowptr + 1, bsum, N);
    k_scan2<<<1, 256, 0, stream>>>(bsum, bofs, nchunk);
    k_scan3<<<nchunk, 256, 0, stream>>>(rowptr, bofs, N);
    k_scatter<<<(E + 255) / 256, 256, 0, stream>>>(idx0, idx1, rowptr, fill, sidx1, E);
    k_fillsnode<<<(N + 255) / 256, 256, 0, stream>>>(rowptr, snode, N);

    // graph CSR
    k_gscan<<<1, 128, 0, stream>>>(gcount, gptr);
    k_gscatter<<<(N + 127) / 128, 128, 0, stream>>>(batch, gptr, gfill, gnodes, N);

    // BN1 stats (8-wide fp8 gathers) + finalize
    const int STATS_BLOCKS = 2048;              // x4 waves = 8192 slots
    int per_slot = ((E + STATS_BLOCKS * 4 - 1) / (STATS_BLOCKS * 4) + 7) & ~7;  // 8-aligned
    k_stats<<<STATS_BLOCKS, 256, 0, stream>>>(Apk, Cp8, snode, sidx1, bn1_sum, bn1_sq, E, per_slot);
    k_bn1fin<<<1, 256, 0, stream>>>(bn1_sum, bn1_sq, bn1_g, bn1_b, bn1_scale, bn1_shift, 1.0f / (float)E);

    // fused message + softmax aggregation (2 nodes per block)
    k_aggr<<<(N + 1) / 2, 128, 0, stream>>>(Apk, Cp8, rowptr, sidx1, bn1_scale, bn1_shift, aggr_t, outbuf, N);

    // BN2 + residual/softplus + pool
    k_bn2stats<<<(N + 63) / 64, 128, 0, stream>>>(outbuf, bn2_sum, bn2_sq, N);
    k_bn2fin<<<1, 128, 0, stream>>>(bn2_sum, bn2_sq, bn2_g, bn2_b, bn2_scale, bn2_shift, 1.0f / (float)N);
    k_h2pool<16><<<128 * 16, 128, 0, stream>>>(outbuf, h, gptr, gnodes, bn2_scale, bn2_shift, pooled);

    // head
    k_head<<<128, 256, 0, stream>>>(pooled, gcount, l1_w, l1_b, out_w, out_b, (float*)d_out);
}

// Round 13
// 595.540 us; speedup vs baseline: 1.6953x; 1.0405x over previous
//
#include <hip/hip_runtime.h>
#include <hip/hip_bf16.h>

// CrystalHypergraphConv — MI355X implementation.
//
// z[e] = A[idx0[e]] + C[idx1[e]];  A = h@(W0+W2)+b [N,256] f32-packed;
// C = cf@W1 [NHE,256] fp8-e4m3-packed (lane l owns {2l,2l+1,128+2l,129+2l}).
//
// R12 -> R13: ledger showed ~250us unaccounted across ~22 launches; k_aggr is
// at its transcendental roofline (75% VALUBusy, 10 trans/edge/lane).
//  * Fused GEMM chains: x->h->Apk and hedge->(cf)->Cp8 are ONE kernel each
//    (GEMM1 C-layout -> A-layout via padded LDS tile; cf never hits HBM).
//  * Frag-major B tables (k_prepw): B loads 128 scalar u16 -> 16 b128/lane.
//  * CSR build collapsed: one single-block scan kernel (rowptr+gptr), one
//    scatter kernel (sidx1+snode+gnodes). Dispatches 22 -> 14.
//  * k_aggr: 256-thr blocks (4 nodes/block).

#define EPS_BN 1e-5f
#define LOG2E 1.4426950408889634f
#define LN2   0.6931471805599453f

typedef __attribute__((ext_vector_type(8))) short bf16x8;
typedef __attribute__((ext_vector_type(4))) float f32x4;
typedef __attribute__((ext_vector_type(2))) float f32x2;

__device__ __forceinline__ float fexp2(float x) {
#if __has_builtin(__builtin_amdgcn_exp2f)
    return __builtin_amdgcn_exp2f(x);
#else
    return __expf(x * LN2);
#endif
}
__device__ __forceinline__ float flog2(float x) {
#if __has_builtin(__builtin_amdgcn_logf)
    return __builtin_amdgcn_logf(x);
#else
    return __logf(x) * LOG2E;
#endif
}
__device__ __forceinline__ float softplus_fast(float x) {
    return LN2 * flog2(1.f + fexp2(x * LOG2E));
}

__device__ __forceinline__ unsigned short f2bf(float f) {
    unsigned u = __float_as_uint(f);
    unsigned r = (u + 0x7fffu + ((u >> 16) & 1u)) >> 16;   // RNE
    return (unsigned short)r;
}

// ---- fp8 e4m3 encode/decode (OCP; HW path on gfx950) ----
#if __has_builtin(__builtin_amdgcn_cvt_pk_f32_fp8) && __has_builtin(__builtin_amdgcn_cvt_pk_fp8_f32)
#define HW_FP8 1
#else
#define HW_FP8 0
#endif

__device__ __forceinline__ unsigned char f2fp8(float f) {
#if HW_FP8
    int r = __builtin_amdgcn_cvt_pk_fp8_f32(f, f, 0, false);
    return (unsigned char)(r & 0xff);
#else
    unsigned u = __float_as_uint(f);
    unsigned s = (u >> 24) & 0x80u;
    float af = fabsf(f);
    if (!(af >= 0.015625f)) {
        int m = (int)rintf(af * 512.f);
        if (m > 7) m = 7;
        return (unsigned char)(s | (unsigned)m);
    }
    if (af > 448.f) return (unsigned char)(s | 0x7e);
    unsigned au = __float_as_uint(af);
    unsigned r = au + 0x7ffffu + ((au >> 20) & 1u);
    int e8 = (int)(r >> 23) - 120;
    unsigned m = (r >> 20) & 7u;
    if (e8 > 15 || (e8 == 15 && m == 7)) return (unsigned char)(s | 0x7e);
    return (unsigned char)(s | ((unsigned)e8 << 3) | m);
#endif
}

__device__ __forceinline__ void fp8quad(unsigned p, float& a, float& b, float& c, float& d) {
#if HW_FP8
    f32x2 lo = __builtin_amdgcn_cvt_pk_f32_fp8((int)p, false);
    f32x2 hi = __builtin_amdgcn_cvt_pk_f32_fp8((int)p, true);
    a = lo.x; b = lo.y; c = hi.x; d = hi.y;
#else
    auto dec = [](unsigned byte) -> float {
        unsigned s = (byte & 0x80u) << 24;
        unsigned em = byte & 0x7fu;
        float nrm = __uint_as_float(s | ((em << 20) + 0x3C000000u));
        float sub = __uint_as_float(s | 0x3F800000u) * (float)em * 0.001953125f;
        return (em >= 8) ? nrm : sub;
    };
    a = dec(p & 0xff); b = dec((p >> 8) & 0xff);
    c = dec((p >> 16) & 0xff); d = dec(p >> 24);
#endif
}

__device__ __forceinline__ int perm256(int j) {
    return (j < 128) ? ((j >> 1) * 4 + (j & 1)) : (((j - 128) >> 1) * 4 + 2 + (j & 1));
}

// ---------------- weight prep: frag-major bf16 B tables ----------------
// layout: flat = (((w*NKC + kc)*CT + c)*64 + l)*8 + j
//   k = kc*32 + ((l>>4)&3)*8 + j ; n = (w*CT + c)*16 + (l&15)
// embB: NKC=3 CT=2 (12288); bembB: NKC=2 CT=2 (8192); waB/wcB: NKC=4 CT=4 (32768 ea)
__global__ __launch_bounds__(256) void k_prepw(const float* __restrict__ ew, const float* __restrict__ bw,
                                               const float* __restrict__ lw,
                                               unsigned short* __restrict__ embB, unsigned short* __restrict__ bembB,
                                               unsigned short* __restrict__ waB, unsigned short* __restrict__ wcB) {
    int i = blockIdx.x * 256 + threadIdx.x;          // 0..81919
    if (i >= 81920) return;
    unsigned short* dst;
    int f, NKC, CT, mode;
    if (i < 12288)      { dst = embB;  f = i;         NKC = 3; CT = 2; mode = 0; }
    else if (i < 20480) { dst = bembB; f = i - 12288; NKC = 2; CT = 2; mode = 1; }
    else if (i < 53248) { dst = waB;   f = i - 20480; NKC = 4; CT = 4; mode = 2; }
    else                { dst = wcB;   f = i - 53248; NKC = 4; CT = 4; mode = 3; }
    int j = f & 7, l = (f >> 3) & 63;
    int r2 = f >> 9;
    int c = r2 % CT;
    int r3 = r2 / CT;
    int kc = r3 % NKC, w = r3 / NKC;
    int k = kc * 32 + ((l >> 4) & 3) * 8 + j;
    int n = (w * CT + c) * 16 + (l & 15);
    float v;
    if (mode == 0)      v = (k < 92) ? ew[k * 128 + n] : 0.f;
    else if (mode == 1) v = (k < 40) ? bw[k * 128 + n] : 0.f;
    else if (mode == 2) v = lw[k * 256 + n] + lw[(k + 256) * 256 + n];
    else                v = lw[(k + 128) * 256 + n];
    dst[f] = f2bf(v);
}

// ---------------- fused 2-stage MFMA GEMM ----------------
// stage1: in[M,KIN] @ B1[NKC1*32 x 128] + bias1 -> t[M,128]  (bf16 in LDS)
// stage2: t @ B2[128 x 256] + bias2 -> packed out (OMODE2: 1 = f32 Apk + write h; 2 = fp8 Cp8)
template<int KIN, int NKC1, int OMODE2>
__global__ __launch_bounds__(256) void mfma_fused(
    const float* __restrict__ in, const unsigned short* __restrict__ B1, const float* __restrict__ bias1,
    const unsigned short* __restrict__ B2, const float* __restrict__ bias2,
    float* __restrict__ hout, void* __restrict__ out2, int M)
{
    const int r0 = blockIdx.x * 32;
    const int t = threadIdx.x;
    const int w = t >> 6;
    const int l = t & 63;
    const int m = l & 15, q = l >> 4;

    __shared__ __align__(16) unsigned short als[32 * NKC1 * 32];   // frag-major stage1 A
    __shared__ __align__(16) unsigned short hls[32 * 136];         // row-major t, padded (+8)

    // stage A: 32 rows x NKC1*32 k, f32 -> bf16, frag-major
    const int KP = NKC1 * 32;
    for (int i = t; i < 32 * KP; i += 256) {
        int r = i / KP, k = i - r * KP;
        int gr = r0 + r;
        float v = (gr < M && k < KIN) ? in[(size_t)gr * KIN + k] : 0.f;
        int idx = (((r >> 4) * NKC1 + (k >> 5)) * 64 + ((k >> 3) & 3) * 16 + (r & 15)) * 8 + (k & 7);
        als[idx] = f2bf(v);
    }
    // B1 frags
    bf16x8 b1[NKC1][2];
    const bf16x8* B1f = (const bf16x8*)B1;
#pragma unroll
    for (int kc = 0; kc < NKC1; kc++)
#pragma unroll
        for (int c = 0; c < 2; c++)
            b1[kc][c] = B1f[((w * NKC1 + kc) * 2 + c) * 64 + l];
    __syncthreads();

    f32x4 acc1[2][2];
#pragma unroll
    for (int c = 0; c < 2; c++) { acc1[c][0] = (f32x4){0.f,0.f,0.f,0.f}; acc1[c][1] = (f32x4){0.f,0.f,0.f,0.f}; }
    const bf16x8* af = (const bf16x8*)als;
#pragma unroll
    for (int kc = 0; kc < NKC1; kc++) {
        bf16x8 a0 = af[kc * 64 + l];
        bf16x8 a1 = af[(NKC1 + kc) * 64 + l];
#pragma unroll
        for (int c = 0; c < 2; c++) {
            acc1[c][0] = __builtin_amdgcn_mfma_f32_16x16x32_bf16(a0, b1[kc][c], acc1[c][0], 0, 0, 0);
            acc1[c][1] = __builtin_amdgcn_mfma_f32_16x16x32_bf16(a1, b1[kc][c], acc1[c][1], 0, 0, 0);
        }
    }
    // epilogue 1: t -> hls (bf16) [+ h global if OMODE2==1]
#pragma unroll
    for (int c = 0; c < 2; c++) {
        int n1 = (w * 2 + c) * 16 + m;
        float bv = bias1[n1];
#pragma unroll
        for (int hh = 0; hh < 2; hh++) {
#pragma unroll
            for (int r = 0; r < 4; r++) {
                int row = hh * 16 + q * 4 + r;
                float val = acc1[c][hh][r] + bv;
                hls[row * 136 + n1] = f2bf(val);
                if (OMODE2 == 1 && r0 + row < M) hout[(size_t)(r0 + row) * 128 + n1] = val;
            }
        }
    }
    __syncthreads();

    // stage 2: B2 frags + MFMA from hls
    bf16x8 b2[4][4];
    const bf16x8* B2f = (const bf16x8*)B2;
#pragma unroll
    for (int kc = 0; kc < 4; kc++)
#pragma unroll
        for (int c = 0; c < 4; c++)
            b2[kc][c] = B2f[((w * 4 + kc) * 4 + c) * 64 + l];

    f32x4 acc2[4][2];
#pragma unroll
    for (int c = 0; c < 4; c++) { acc2[c][0] = (f32x4){0.f,0.f,0.f,0.f}; acc2[c][1] = (f32x4){0.f,0.f,0.f,0.f}; }
#pragma unroll
    for (int kc = 0; kc < 4; kc++) {
        bf16x8 a0 = *(const bf16x8*)(hls + m * 136 + kc * 32 + q * 8);
        bf16x8 a1 = *(const bf16x8*)(hls + (m + 16) * 136 + kc * 32 + q * 8);
#pragma unroll
        for (int c = 0; c < 4; c++) {
            acc2[c][0] = __builtin_amdgcn_mfma_f32_16x16x32_bf16(a0, b2[kc][c], acc2[c][0], 0, 0, 0);
            acc2[c][1] = __builtin_amdgcn_mfma_f32_16x16x32_bf16(a1, b2[kc][c], acc2[c][1], 0, 0, 0);
        }
    }
#pragma unroll
    for (int c = 0; c < 4; c++) {
        int n = (w * 4 + c) * 16 + m;
        float bv = bias2 ? bias2[n] : 0.f;
        int pj = perm256(n);
#pragma unroll
        for (int hh = 0; hh < 2; hh++) {
#pragma unroll
            for (int r = 0; r < 4; r++) {
                int row = r0 + hh * 16 + q * 4 + r;
                if (row < M) {
                    float val = acc2[c][hh][r] + bv;
                    if (OMODE2 == 1) ((float*)out2)[(size_t)row * 256 + pj] = val;
                    else             ((unsigned char*)out2)[(size_t)row * 256 + pj] = f2fp8(val);
                }
            }
        }
    }
}

// ---------------- histograms: idx0 -> hist, batch -> gcount ----------------
__global__ __launch_bounds__(256) void k_hist2(const int* __restrict__ idx0, const int* __restrict__ batch,
                                               int* __restrict__ hist, int* __restrict__ gcount, int E, int N) {
    int i = blockIdx.x * 256 + threadIdx.x;
    if (i < E) atomicAdd(&hist[idx0[i]], 1);
    if (i < N) atomicAdd(&gcount[batch[i]], 1);
}

// ---------------- single-block scan: hist -> rowptr (N+1), gcount -> gptr (129) ----------------
__global__ __launch_bounds__(1024) void k_scanall(const int* __restrict__ hist, int* __restrict__ rowptr,
                                                  const int* __restrict__ gcount, int* __restrict__ gptr, int N) {
    __shared__ int s[1024];
    const int t = threadIdx.x;
    const int PER = (N + 1023) >> 10;
    const int b0 = t * PER;
    const int b1 = min(b0 + PER, N);
    int sum = 0;
    for (int i = b0; i < b1; i++) sum += hist[i];
    s[t] = sum;
    __syncthreads();
    for (int ofs = 1; ofs < 1024; ofs <<= 1) {
        int v = (t >= ofs) ? s[t - ofs] : 0;
        __syncthreads();
        s[t] += v;
        __syncthreads();
    }
    int run = s[t] - sum;                      // exclusive prefix
    for (int i = b0; i < b1; i++) {
        run += hist[i];
        rowptr[i + 1] = run;
    }
    if (t == 0) rowptr[0] = 0;
    // gptr scan (128 entries), reuse s
    __syncthreads();
    int gv = (t < 128) ? gcount[t] : 0;
    s[t] = gv;
    __syncthreads();
    for (int ofs = 1; ofs < 128; ofs <<= 1) {
        int v = (t >= ofs && t < 128) ? s[t - ofs] : 0;
        __syncthreads();
        if (t < 128) s[t] += v;
        __syncthreads();
    }
    if (t < 128) gptr[t + 1] = s[t];
    if (t == 0) gptr[0] = 0;
}

// ---------------- merged scatter: sidx1 (atomics), snode fill, gnodes scatter ----------------
__global__ __launch_bounds__(256) void k_scatter2(const int* __restrict__ idx0, const int* __restrict__ idx1,
                                                  const int* __restrict__ batch,
                                                  const int* __restrict__ rowptr, const int* __restrict__ gptr,
                                                  int* __restrict__ fill, int* __restrict__ gfill,
                                                  int* __restrict__ sidx1, int* __restrict__ snode,
                                                  int* __restrict__ gnodes, int E, int N) {
    int i = blockIdx.x * 256 + threadIdx.x;
    if (i < E) {
        int n = idx0[i];
        int pos = rowptr[n] + atomicAdd(&fill[n], 1);
        sidx1[pos] = idx1[i];
    }
    if (i < N) {
        int a = rowptr[i], b = rowptr[i + 1];
        for (int e = a; e < b; e++) snode[e] = i;
        int g = batch[i];
        int pos = gptr[g] + atomicAdd(&gfill[g], 1);
        gnodes[pos] = i;
    }
}

// ---------------- BN1 stats: run-amortized A, 8-wide batched fp8 gathers ----------------
__global__ __launch_bounds__(256) void k_stats(const float* __restrict__ Apk, const unsigned* __restrict__ Cp8,
                                               const int* __restrict__ snode, const int* __restrict__ sidx1,
                                               float* __restrict__ gsum, float* __restrict__ gsq,
                                               int E, int per_slot) {
    __shared__ float4 lsm4[256], lsq4[256];
    const int t = threadIdx.x;
    const int s = t >> 6, l = t & 63;
    const float4* A4 = (const float4*)Apk;
    const long base = (long)(blockIdx.x * 4 + s) * per_slot;
    const int e0 = (int)min((long)E, base);
    const int e1 = (int)min((long)E, base + per_slot);
    float4 sm = {0.f, 0.f, 0.f, 0.f}, s2 = {0.f, 0.f, 0.f, 0.f};
    float4 csr = {0.f, 0.f, 0.f, 0.f};
    float4 a = {0.f, 0.f, 0.f, 0.f};
    int cur_n = -1, runk = 0;

    auto flush = [&]() {
        if (runk) {
            float fk = (float)runk;
            sm.x += fmaf(fk, a.x, csr.x);
            sm.y += fmaf(fk, a.y, csr.y);
            sm.z += fmaf(fk, a.z, csr.z);
            sm.w += fmaf(fk, a.w, csr.w);
            float t0 = fmaf(fk, a.x, 2.f * csr.x); s2.x = fmaf(a.x, t0, s2.x);
            float t1 = fmaf(fk, a.y, 2.f * csr.y); s2.y = fmaf(a.y, t1, s2.y);
            float t2 = fmaf(fk, a.z, 2.f * csr.z); s2.z = fmaf(a.z, t2, s2.z);
            float t3 = fmaf(fk, a.w, 2.f * csr.w); s2.w = fmaf(a.w, t3, s2.w);
        }
    };
    auto proc = [&](int n, unsigned p) {
        if (n != cur_n) {
            flush();
            a = A4[(size_t)n * 64 + l];
            cur_n = n; runk = 0;
            csr.x = 0.f; csr.y = 0.f; csr.z = 0.f; csr.w = 0.f;
        }
        float c0, c1, c2, c3;
        fp8quad(p, c0, c1, c2, c3);
        csr.x += c0; csr.y += c1; csr.z += c2; csr.w += c3;
        s2.x = fmaf(c0, c0, s2.x);
        s2.y = fmaf(c1, c1, s2.y);
        s2.z = fmaf(c2, c2, s2.z);
        s2.w = fmaf(c3, c3, s2.w);
        runk++;
    };

    int e = e0;
    for (; e + 8 <= e1; e += 8) {
        int4 nn0 = *(const int4*)(snode + e);
        int4 nn1 = *(const int4*)(snode + e + 4);
        int4 mm0 = *(const int4*)(sidx1 + e);
        int4 mm1 = *(const int4*)(sidx1 + e + 4);
        unsigned p0 = Cp8[(size_t)mm0.x * 64 + l];
        unsigned p1 = Cp8[(size_t)mm0.y * 64 + l];
        unsigned p2 = Cp8[(size_t)mm0.z * 64 + l];
        unsigned p3 = Cp8[(size_t)mm0.w * 64 + l];
        unsigned p4 = Cp8[(size_t)mm1.x * 64 + l];
        unsigned p5 = Cp8[(size_t)mm1.y * 64 + l];
        unsigned p6 = Cp8[(size_t)mm1.z * 64 + l];
        unsigned p7 = Cp8[(size_t)mm1.w * 64 + l];
        proc(nn0.x, p0); proc(nn0.y, p1); proc(nn0.z, p2); proc(nn0.w, p3);
        proc(nn1.x, p4); proc(nn1.y, p5); proc(nn1.z, p6); proc(nn1.w, p7);
    }
    for (; e < e1; e++) proc(snode[e], Cp8[(size_t)sidx1[e] * 64 + l]);
    flush();

    lsm4[t] = sm;
    lsq4[t] = s2;
    __syncthreads();
    const float* fm = (const float*)lsm4;
    const float* fq = (const float*)lsq4;
    float vs = fm[t] + fm[256 + t] + fm[512 + t] + fm[768 + t];
    float vq = fq[t] + fq[256 + t] + fq[512 + t] + fq[768 + t];
    atomicAdd(&gsum[t], vs);
    atomicAdd(&gsq[t], vq);
}

__global__ __launch_bounds__(256) void k_bn1fin(const float* __restrict__ sum, const float* __restrict__ sq,
                                                const float* __restrict__ g, const float* __restrict__ b,
                                                float* __restrict__ scale, float* __restrict__ shift, float invE) {
    int j = threadIdx.x;
    int l = j >> 2, k = j & 3;
    int ch = (k < 2) ? (2 * l + k) : (128 + 2 * l + (k - 2));
    float mu = sum[j] * invE;
    float var = sq[j] * invE - mu * mu;
    float sc = g[ch] * rsqrtf(var + EPS_BN);
    scale[j] = sc;
    shift[j] = fmaf(-mu, sc, b[ch]);
}

// ---------------- fused msg + segment softmax aggregation (4 waves/block, 1 node/wave) ----------------
__global__ __launch_bounds__(256) void k_aggr(const float* __restrict__ Apk, const unsigned* __restrict__ Cp8,
                                              const int* __restrict__ rowptr, const int* __restrict__ sidx1,
                                              const float* __restrict__ scale_pk, const float* __restrict__ shift_pk,
                                              const float* __restrict__ tptr, float* __restrict__ out, int N) {
    const int n = blockIdx.x * 4 + (threadIdx.x >> 6);
    if (n >= N) return;
    const int l = threadIdx.x & 63;
    const float t2 = tptr[0] * LOG2E;
    const float4 sc = ((const float4*)scale_pk)[l];
    const float4 sh = ((const float4*)shift_pk)[l];
    const float4 ap = ((const float4*)Apk)[(size_t)n * 64 + l];
    const float sfx = -sc.x * LOG2E, sfy = -sc.y * LOG2E;
    const float bfx = -fmaf(ap.x, sc.x, sh.x) * LOG2E;
    const float bfy = -fmaf(ap.y, sc.y, sh.y) * LOG2E;
    const float scz = sc.z * LOG2E, scw = sc.w * LOG2E;
    const float bcz = fmaf(ap.z, sc.z, sh.z) * LOG2E;
    const float bcw = fmaf(ap.w, sc.w, sh.w) * LOG2E;
    const int e0 = rowptr[n], e1 = rowptr[n + 1];
    float den0 = 0.f, num0 = 0.f, den1 = 0.f, num1 = 0.f;

    auto proc = [&](unsigned p) {
        float c0, c1, c2, c3;
        fp8quad(p, c0, c1, c2, c3);
        float ef0 = fexp2(fmaf(c0, sfx, bfx));
        float ef1 = fexp2(fmaf(c1, sfy, bfy));
        float u0  = fexp2(fmaf(c2, scz, bcz));
        float u1  = fexp2(fmaf(c3, scw, bcw));
        float sig0 = __builtin_amdgcn_rcpf(1.f + ef0);
        float sig1 = __builtin_amdgcn_rcpf(1.f + ef1);
        float sp0 = LN2 * flog2(1.f + u0);
        float sp1 = LN2 * flog2(1.f + u1);
        float msg0 = sig0 * sp0;
        float msg1 = sig1 * sp1;
        float w0 = fexp2(t2 * msg0);
        float w1 = fexp2(t2 * msg1);
        den0 += w0; num0 = fmaf(msg0, w0, num0);
        den1 += w1; num1 = fmaf(msg1, w1, num1);
    };

    if (e1 > e0) {
        unsigned cur[4];
        int cb = min(e1 - e0, 4);
#pragma unroll
        for (int i = 0; i < 4; i++)
            if (i < cb) cur[i] = Cp8[(size_t)sidx1[e0 + i] * 64 + l];
        for (int eb = e0; eb < e1; eb += 4) {
            int nb = min(max(e1 - (eb + 4), 0), 4);
            unsigned nxt[4];
#pragma unroll
            for (int i = 0; i < 4; i++)
                if (i < nb) nxt[i] = Cp8[(size_t)sidx1[eb + 4 + i] * 64 + l];
            int pb = min(e1 - eb, 4);
#pragma unroll
            for (int i = 0; i < 4; i++)
                if (i < pb) proc(cur[i]);
#pragma unroll
            for (int i = 0; i < 4; i++) cur[i] = nxt[i];
        }
    }
    float2 o;
    o.x = (e1 > e0) ? num0 / den0 : 0.f;
    o.y = (e1 > e0) ? num1 / den1 : 0.f;
    ((float2*)out)[(size_t)n * 64 + l] = o;
}

// ---------------- BN2 ----------------
__global__ __launch_bounds__(128) void k_bn2stats(const float* __restrict__ out, float* __restrict__ sum,
                                                  float* __restrict__ sq, int N) {
    const int c = threadIdx.x;
    const int n0 = blockIdx.x * 64;
    const int nend = min(n0 + 64, N);
    float sm = 0.f, s2 = 0.f;
    for (int n = n0; n < nend; n++) {
        float v = out[(size_t)n * 128 + c];
        sm += v;
        s2 = fmaf(v, v, s2);
    }
    atomicAdd(&sum[c], sm);
    atomicAdd(&sq[c], s2);
}

__global__ __launch_bounds__(128) void k_bn2fin(const float* __restrict__ sum, const float* __restrict__ sq,
                                                const float* __restrict__ g, const float* __restrict__ b,
                                                float* __restrict__ scale, float* __restrict__ shift, float invN) {
    int j = threadIdx.x;
    float mu = sum[j] * invN;
    float var = sq[j] * invN - mu * mu;
    float sc = g[j] * rsqrtf(var + EPS_BN);
    scale[j] = sc;
    shift[j] = fmaf(-mu, sc, b[j]);
}

// ---------------- residual+softplus + mean-pool ----------------
template<int SPLIT>
__global__ __launch_bounds__(128) void k_h2pool(const float* __restrict__ out, const float* __restrict__ h,
                                                const int* __restrict__ gptr, const int* __restrict__ gnodes,
                                                const float* __restrict__ scale, const float* __restrict__ shift,
                                                float* __restrict__ pooled) {
    const int g = blockIdx.x & 127;
    const int sp = blockIdx.x >> 7;
    const int c = threadIdx.x;
    const float sc = scale[c], sh = shift[c];
    const int i0 = gptr[g], i1 = gptr[g + 1];
    float acc = 0.f;
    for (int i = i0 + sp; i < i1; i += SPLIT) {
        int n = gnodes[i];
        float v = fmaf(out[(size_t)n * 128 + c], sc, sh) + h[(size_t)n * 128 + c];
        acc += softplus_fast(v);
    }
    if (acc != 0.f) atomicAdd(&pooled[g * 128 + c], acc);
}

// ---------------- head ----------------
__global__ __launch_bounds__(256) void k_head(const float* __restrict__ pooled, const int* __restrict__ gcount,
                                              const float* __restrict__ l1w, const float* __restrict__ l1b,
                                              const float* __restrict__ outw, const float* __restrict__ outb,
                                              float* __restrict__ dout) {
    __shared__ float p[128];
    __shared__ float red[256];
    const int g = blockIdx.x;
    const int j = threadIdx.x;
    if (j < 128) {
        float cnt = (float)max(gcount[g], 1);
        p[j] = pooled[g * 128 + j] / cnt;
    }
    __syncthreads();
    float acc = l1b[j];
    for (int k = 0; k < 128; k++) acc = fmaf(p[k], l1w[k * 256 + j], acc);
    red[j] = softplus_fast(acc) * outw[j];
    __syncthreads();
    for (int s = 128; s > 0; s >>= 1) {
        if (j < s) red[j] += red[j + s];
        __syncthreads();
    }
    if (j == 0) dout[g] = red[0] + outb[0];
}

// ---------------- launch ----------------
extern "C" void kernel_launch(void* const* d_in, const int* in_sizes, int n_in,
                              void* d_out, int out_size, void* d_ws, size_t ws_size,
                              hipStream_t stream) {
    const float* x        = (const float*)d_in[0];
    const float* hedge    = (const float*)d_in[1];
    const int*   iri      = (const int*)d_in[2];
    const int*   batch    = (const int*)d_in[3];
    const float* embed_w  = (const float*)d_in[5];
    const float* embed_b  = (const float*)d_in[6];
    const float* bembed_w = (const float*)d_in[7];
    const float* bembed_b = (const float*)d_in[8];
    const float* lin_w    = (const float*)d_in[9];
    const float* lin_b    = (const float*)d_in[10];
    const float* bn1_g    = (const float*)d_in[11];
    const float* bn1_b    = (const float*)d_in[12];
    const float* bn2_g    = (const float*)d_in[13];
    const float* bn2_b    = (const float*)d_in[14];
    const float* aggr_t   = (const float*)d_in[15];
    const float* l1_w     = (const float*)d_in[16];
    const float* l1_b     = (const float*)d_in[17];
    const float* out_w    = (const float*)d_in[18];
    const float* out_b    = (const float*)d_in[19];

    const int N   = in_sizes[0] / 92;
    const int NHE = in_sizes[1] / 40;
    const int E   = in_sizes[2] / 3;
    const int* idx0 = iri;
    const int* idx1 = iri + E;

    float* ws = (float*)d_ws;
    size_t off = 0;
    auto alloc = [&](size_t elems) -> float* {
        float* p = ws + off;
        off += (elems + 63) & ~(size_t)63;
        return p;
    };
    float* h      = alloc((size_t)N * 128);
    float* Apk    = alloc((size_t)N * 256);        // packed f32
    unsigned* Cp8 = (unsigned*)alloc((size_t)NHE * 64);   // packed fp8
    unsigned short* embB  = (unsigned short*)alloc(6144);    // 12288 u16 frag-major
    unsigned short* bembB = (unsigned short*)alloc(4096);    // 8192 u16
    unsigned short* waB   = (unsigned short*)alloc(16384);   // 32768 u16
    unsigned short* wcB   = (unsigned short*)alloc(16384);
    int*   rowptr = (int*)alloc((size_t)N + 1);
    int*   snode  = (int*)alloc((size_t)E + 8);
    int*   sidx1  = (int*)alloc((size_t)E + 8);
    int*   gptr   = (int*)alloc(129);
    int*   gnodes = (int*)alloc((size_t)N);
    float* bn1_scale = alloc(256);
    float* bn1_shift = alloc(256);
    float* bn2_scale = alloc(128);
    float* bn2_shift = alloc(128);
    float* outbuf = alloc((size_t)N * 128);
    // contiguous zero region
    float* zbase  = ws + off;
    int*   hist   = (int*)alloc((size_t)N);
    int*   fill   = (int*)alloc((size_t)N);
    int*   gfill  = (int*)alloc(128);
    float* bn1_sum = alloc(256);
    float* bn1_sq  = alloc(256);
    float* bn2_sum = alloc(128);
    float* bn2_sq  = alloc(128);
    float* pooled  = alloc(128 * 128);
    int*   gcount  = (int*)alloc(128);
    size_t zbytes = (size_t)((ws + off) - zbase) * sizeof(float);
    (void)ws_size;  // ~125MB; fit verified R1-R12 at larger sizes

    hipMemsetAsync(zbase, 0, zbytes, stream);

    // frag-major bf16 weight prep + fused MFMA GEMM chains
    k_prepw<<<320, 256, 0, stream>>>(embed_w, bembed_w, lin_w, embB, bembB, waB, wcB);
    const int mtN   = (N + 31) / 32;
    const int mtNHE = (NHE + 31) / 32;
    mfma_fused<92, 3, 1><<<mtN, 256, 0, stream>>>(x, embB, embed_b, waB, lin_b, h, Apk, N);
    mfma_fused<40, 2, 2><<<mtNHE, 256, 0, stream>>>(hedge, bembB, bembed_b, wcB, nullptr, nullptr, Cp8, NHE);

    // CSR build: histograms -> single-block scans -> merged scatter
    k_hist2<<<(E + 255) / 256, 256, 0, stream>>>(idx0, batch, hist, gcount, E, N);
    k_scanall<<<1, 1024, 0, stream>>>(hist, rowptr, gcount, gptr, N);
    k_scatter2<<<(E + 255) / 256, 256, 0, stream>>>(idx0, idx1, batch, rowptr, gptr,
                                                    fill, gfill, sidx1, snode, gnodes, E, N);

    // BN1 stats (8-wide fp8 gathers) + finalize
    const int STATS_BLOCKS = 2048;
    int per_slot = ((E + STATS_BLOCKS * 4 - 1) / (STATS_BLOCKS * 4) + 7) & ~7;
    k_stats<<<STATS_BLOCKS, 256, 0, stream>>>(Apk, Cp8, snode, sidx1, bn1_sum, bn1_sq, E, per_slot);
    k_bn1fin<<<1, 256, 0, stream>>>(bn1_sum, bn1_sq, bn1_g, bn1_b, bn1_scale, bn1_shift, 1.0f / (float)E);

    // fused message + softmax aggregation (4 nodes per block)
    k_aggr<<<(N + 3) / 4, 256, 0, stream>>>(Apk, Cp8, rowptr, sidx1, bn1_scale, bn1_shift, aggr_t, outbuf, N);

    // BN2 + residual/softplus + pool
    k_bn2stats<<<(N + 63) / 64, 128, 0, stream>>>(outbuf, bn2_sum, bn2_sq, N);
    k_bn2fin<<<1, 128, 0, stream>>>(bn2_sum, bn2_sq, bn2_g, bn2_b, bn2_scale, bn2_shift, 1.0f / (float)N);
    k_h2pool<16><<<128 * 16, 128, 0, stream>>>(outbuf, h, gptr, gnodes, bn2_scale, bn2_shift, pooled);

    // head
    k_head<<<128, 256, 0, stream>>>(pooled, gcount, l1_w, l1_b, out_w, out_b, (float*)d_out);
}